// Round 3
// baseline (1098.072 us; speedup 1.0000x reference)
//
#include <hip/hip_runtime.h>
#include <hip/hip_bf16.h>
#include <math.h>

// ---------------------------------------------------------------------------
// MultiDirectionalGridAttention. Inputs/outputs are FP32 (per reference);
// compute core is bf16 MFMA with fp32 accumulation.
// B=4, T=1024 (32x32 grid), D=1024, NH=16, hd=64.
//
// Pipeline:
//   cvt x -> x_c (bf16)
//   for dir: cvt w_qkv -> wq_c; qkv GEMM; flash attention (causal in permuted
//            order; lr=identity, rl=reverse, td=transpose, bu=rev-transpose)
//   cvt w_o x4; out-proj GEMM (z-batched) -> concat
//   cvt w_gate; gate GEMM: gated = sigmoid(concat@wg^T + b[f32]) * concat
//   cvt w_out; w_out GEMM: d_out[f32] = gated@wout^T + x[f32]
//   rmsnorm fp32 in-place on d_out
//
// ws layout (peak 102 MB), phase-overlaid:
//   [0..8)    x_c          (dies after last qkv GEMM)
//   [8..14)   wq_c slot    (reconverted per dir)
//   [14..38)  qkv          (dies after last attention)
//   [38..70)  y / gated
//   [70..102) concat
//   [0..8)    wo_c   (reuse, after dir loop)
//   [0..32)   wg_c   (reuse, after out-proj)
//   [0..8)    wout_c (reuse, after gate GEMM)
// ---------------------------------------------------------------------------

typedef __bf16 bf16_t;
typedef __bf16 bf16x8 __attribute__((ext_vector_type(8)));
typedef float  f32x4  __attribute__((ext_vector_type(4)));

#define MFMA16(a, b, c) __builtin_amdgcn_mfma_f32_16x16x32_bf16((a), (b), (c), 0, 0, 0)

__device__ __forceinline__ void async16(const bf16_t* g, bf16_t* l) {
  __builtin_amdgcn_global_load_lds((const __attribute__((address_space(1))) void*)g,
                                   (__attribute__((address_space(3))) void*)l,
                                   16, 0, 0);
}

struct Ptr4 { const bf16_t* p[4]; };

// --------------------------- fp32 -> bf16 convert ---------------------------
__global__ __launch_bounds__(256) void cvt_k(const float* __restrict__ in,
                                             bf16_t* __restrict__ out, int n8) {
  const int i = blockIdx.x * 256 + threadIdx.x;
  if (i >= n8) return;
  const float4 a = ((const float4*)in)[i * 2];
  const float4 b = ((const float4*)in)[i * 2 + 1];
  bf16x8 o;
  o[0] = (bf16_t)a.x; o[1] = (bf16_t)a.y; o[2] = (bf16_t)a.z; o[3] = (bf16_t)a.w;
  o[4] = (bf16_t)b.x; o[5] = (bf16_t)b.y; o[6] = (bf16_t)b.z; o[7] = (bf16_t)b.w;
  ((bf16x8*)out)[i] = o;
}

// ---------------------------------------------------------------------------
// C = A * B^T, bf16 in, fp32 acc. 128x128 tile, BK=32, 4 waves 2x2 (m97).
// MODE 0: store bf16 C (at Cv + z*sCz)
// MODE 1: g = sigmoid(acc + bias[n]); store bf16 g * gin[m][n]
// MODE 2: store fp32 acc + resid[m][n]
// ---------------------------------------------------------------------------
template <int MODE>
__global__ __launch_bounds__(256) void gemm_bt(
    const bf16_t* __restrict__ A, long sAz, int lda,
    Ptr4 B4, int ldb,
    void* __restrict__ Cv, long sCz, int ldc, int K,
    const float* __restrict__ bias,
    const bf16_t* __restrict__ gin,
    const float* __restrict__ resid) {
  constexpr int BM = 128, BN = 128, BK = 32;
  __shared__ __align__(16) bf16_t sA[BM * BK];
  __shared__ __align__(16) bf16_t sB[BN * BK];

  const int z = blockIdx.z;
  const bf16_t* Ap = A + (long)z * sAz;
  const bf16_t* Bp = B4.p[z];
  const int tid = threadIdx.x;
  const int wave = tid >> 6, lane = tid & 63;
  const int lane15 = lane & 15, quad = lane >> 4;
  const int bm = blockIdx.y * BM, bn = blockIdx.x * BN;
  const int wm = (wave >> 1) * 64, wn = (wave & 1) * 64;

  f32x4 acc[4][4];
#pragma unroll
  for (int i = 0; i < 4; i++)
#pragma unroll
    for (int j = 0; j < 4; j++) acc[i][j] = (f32x4){0.f, 0.f, 0.f, 0.f};

  // staging: lane l -> lds byte wave*1024 + l*16 (wave-uniform + lane*16)
  const int srow = wave * 16 + (lane >> 2);
  const int skoff = (lane & 3) * 8;
  const bf16_t* ga = Ap + (long)(bm + srow) * lda + skoff;
  const bf16_t* gb = Bp + (long)(bn + srow) * ldb + skoff;
  bf16_t* la = &sA[srow * BK + skoff];
  bf16_t* lb = &sB[srow * BK + skoff];

  for (int k0 = 0; k0 < K; k0 += BK) {
    __syncthreads();  // previous iteration's LDS reads complete
    async16(ga + k0, la);
    async16(ga + k0 + (long)64 * lda, la + 64 * BK);
    async16(gb + k0, lb);
    async16(gb + k0 + (long)64 * ldb, lb + 64 * BK);
    __syncthreads();  // barrier drains vmcnt: staging visible

    bf16x8 af[4], bfv[4];
#pragma unroll
    for (int i = 0; i < 4; i++)
      af[i] = *(const bf16x8*)&sA[(wm + i * 16 + lane15) * BK + quad * 8];
#pragma unroll
    for (int j = 0; j < 4; j++)
      bfv[j] = *(const bf16x8*)&sB[(wn + j * 16 + lane15) * BK + quad * 8];
#pragma unroll
    for (int i = 0; i < 4; i++)
#pragma unroll
      for (int j = 0; j < 4; j++)
        acc[i][j] = MFMA16(af[i], bfv[j], acc[i][j]);
  }

  // C/D layout: row = quad*4 + reg, col = lane15 (m89-verified)
#pragma unroll
  for (int i = 0; i < 4; i++) {
#pragma unroll
    for (int r = 0; r < 4; r++) {
      const int row = bm + wm + i * 16 + quad * 4 + r;
      const long rb = (long)row * ldc;
#pragma unroll
      for (int j = 0; j < 4; j++) {
        const int col = bn + wn + j * 16 + lane15;
        const float v = acc[i][j][r];
        if constexpr (MODE == 0) {
          ((bf16_t*)Cv + (long)z * sCz)[rb + col] = (bf16_t)v;
        } else if constexpr (MODE == 1) {
          const float g = 1.f / (1.f + __expf(-(v + bias[col])));
          ((bf16_t*)Cv)[rb + col] = (bf16_t)(g * (float)gin[rb + col]);
        } else {
          ((float*)Cv)[rb + col] = v + resid[rb + col];
        }
      }
    }
  }
}

// ---------------------------------------------------------------------------
// Causal-order position p -> token index t.
// dir0 lr: t=p; dir1 rl: t=1023-p; dir2 td: transpose; dir3 bu: transpose(1023-p)
// ---------------------------------------------------------------------------
__device__ __forceinline__ int perm_t(int p, int dir) {
  int q = (dir & 1) ? (1023 - p) : p;
  if (dir >= 2) q = ((q & 31) << 5) | (q >> 5);
  return q;
}

// ---------------------------------------------------------------------------
// Flash attention, causal in permuted order. Block = 4 waves, wave owns 16 q
// rows. K-tiles of 32 keys: K staged natural (j,d), V staged transposed (d,j).
// qkv row layout: [q(1024) | k(1024) | v(1024)], head h at h*64. All bf16.
// ---------------------------------------------------------------------------
__global__ __launch_bounds__(256) void attn_k(const bf16_t* __restrict__ qkv,
                                              bf16_t* __restrict__ y, int dir) {
  const int LDQ = 3072;
  const int bh = blockIdx.y;
  const int b = bh >> 4, h = bh & 15;
  const int qt = blockIdx.x;
  const int tid = threadIdx.x;
  const int wave = tid >> 6, lane = tid & 63;
  const int lane15 = lane & 15, quad = lane >> 4;
  const int hoff = h * 64;
  const bf16_t* base = qkv + (long)b * 1024 * LDQ;

  __shared__ __align__(16) bf16_t sK[32 * 64];
  __shared__ __align__(16) bf16_t sVt[64 * 40];  // V^T, stride 40 (80B rows)
  __shared__ __align__(16) bf16_t sP[4][16 * 32];

  // Q fragments (A-operand: A[m=lane15][k=quad*8+j]), live in regs whole loop
  const int qrow = qt * 64 + wave * 16 + lane15;
  const int qtok = perm_t(qrow, dir);
  const bf16x8 qa0 = *(const bf16x8*)(base + (long)qtok * LDQ + hoff + quad * 8);
  const bf16x8 qa1 = *(const bf16x8*)(base + (long)qtok * LDQ + hoff + 32 + quad * 8);

  const int qrow_c = qt * 64 + wave * 16 + quad * 4;  // + r = C-layout row

  const float FNEG = -1e30f;  // finite sentinel
  float mrow[4] = {FNEG, FNEG, FNEG, FNEG};
  float lrow[4] = {0.f, 0.f, 0.f, 0.f};
  f32x4 o[4];
#pragma unroll
  for (int d = 0; d < 4; d++) o[d] = (f32x4){0.f, 0.f, 0.f, 0.f};

  const int krow_l = wave * 8 + (lane >> 3);
  const int kd = (lane & 7) * 8;
  bf16_t* lk = &sK[krow_l * 64 + kd];
  const int vj = tid & 31, vd0 = (tid >> 5) * 8;

  const int ktiles = qt * 2 + 2;
  for (int kt = 0; kt < ktiles; kt++) {
    const int kbase = kt * 32;
    const bf16x8 kv =
        *(const bf16x8*)(base + (long)perm_t(kbase + krow_l, dir) * LDQ + 1024 + hoff + kd);
    const bf16x8 vv =
        *(const bf16x8*)(base + (long)perm_t(kbase + vj, dir) * LDQ + 2048 + hoff + vd0);
    *(bf16x8*)lk = kv;
#pragma unroll
    for (int i = 0; i < 8; i++) sVt[(vd0 + i) * 40 + vj] = vv[i];
    __syncthreads();

    // S = Q K^T (16q x 32k), two C-frags
    f32x4 s[2];
#pragma unroll
    for (int ns = 0; ns < 2; ns++) {
      const bf16x8 kb0 = *(const bf16x8*)&sK[(ns * 16 + lane15) * 64 + quad * 8];
      const bf16x8 kb1 = *(const bf16x8*)&sK[(ns * 16 + lane15) * 64 + 32 + quad * 8];
      f32x4 t = (f32x4){0.f, 0.f, 0.f, 0.f};
      t = MFMA16(qa0, kb0, t);
      t = MFMA16(qa1, kb1, t);
      s[ns] = t;
    }
#pragma unroll
    for (int ns = 0; ns < 2; ns++) {
      const int kp = kbase + ns * 16 + lane15;
#pragma unroll
      for (int r = 0; r < 4; r++) {
        const float v = s[ns][r] * 0.125f;
        s[ns][r] = (kp <= qrow_c + r) ? v : FNEG;
      }
    }
    float tm[4];
#pragma unroll
    for (int r = 0; r < 4; r++) tm[r] = fmaxf(s[0][r], s[1][r]);
#pragma unroll
    for (int off = 8; off >= 1; off >>= 1)
#pragma unroll
      for (int r = 0; r < 4; r++) tm[r] = fmaxf(tm[r], __shfl_xor(tm[r], off));

    float alpha[4];
#pragma unroll
    for (int r = 0; r < 4; r++) {
      const float mn = fmaxf(mrow[r], tm[r]);
      alpha[r] = __expf(mrow[r] - mn);
      mrow[r] = mn;
    }
    float ps[2][4];
#pragma unroll
    for (int ns = 0; ns < 2; ns++)
#pragma unroll
      for (int r = 0; r < 4; r++) ps[ns][r] = __expf(s[ns][r] - mrow[r]);
    float ts[4];
#pragma unroll
    for (int r = 0; r < 4; r++) ts[r] = ps[0][r] + ps[1][r];
#pragma unroll
    for (int off = 8; off >= 1; off >>= 1)
#pragma unroll
      for (int r = 0; r < 4; r++) ts[r] += __shfl_xor(ts[r], off);
#pragma unroll
    for (int r = 0; r < 4; r++) lrow[r] = lrow[r] * alpha[r] + ts[r];
#pragma unroll
    for (int d = 0; d < 4; d++)
#pragma unroll
      for (int r = 0; r < 4; r++) o[d][r] *= alpha[r];

    // P: C-layout -> bf16 A-layout via per-wave LDS scratch
#pragma unroll
    for (int ns = 0; ns < 2; ns++)
#pragma unroll
      for (int r = 0; r < 4; r++)
        sP[wave][(quad * 4 + r) * 32 + ns * 16 + lane15] = (bf16_t)ps[ns][r];
    __syncthreads();

    const bf16x8 pa = *(const bf16x8*)&sP[wave][lane15 * 32 + quad * 8];
#pragma unroll
    for (int d = 0; d < 4; d++) {
      const bf16x8 vb = *(const bf16x8*)&sVt[(d * 16 + lane15) * 40 + quad * 8];
      o[d] = MFMA16(pa, vb, o[d]);
    }
    __syncthreads();
  }

  // epilogue: O / l, scatter rows back to token order
#pragma unroll
  for (int r = 0; r < 4; r++) {
    const float rinv = 1.f / fmaxf(lrow[r], 1e-20f);
    const int tok = perm_t(qrow_c + r, dir);
    bf16_t* yrow = y + ((long)b * 1024 + tok) * 1024 + hoff;
#pragma unroll
    for (int d = 0; d < 4; d++) yrow[d * 16 + lane15] = (bf16_t)(o[d][r] * rinv);
  }
}

// ---------------------------------------------------------------------------
// RMSNorm over rows of 1024, fp32 in-place (reference is all-fp32 here).
// ---------------------------------------------------------------------------
__global__ __launch_bounds__(256) void rmsnorm_k(float* __restrict__ io,
                                                 const float* __restrict__ w) {
  const int row = blockIdx.x, tid = threadIdx.x;
  float4 v = ((const float4*)(io + (long)row * 1024))[tid];
  float ss = v.x * v.x + v.y * v.y + v.z * v.z + v.w * v.w;
#pragma unroll
  for (int off = 32; off >= 1; off >>= 1) ss += __shfl_xor(ss, off);
  __shared__ float wsum[4];
  if ((tid & 63) == 0) wsum[tid >> 6] = ss;
  __syncthreads();
  const float tot = wsum[0] + wsum[1] + wsum[2] + wsum[3];
  const float norm = rsqrtf(tot * (1.f / 1024.f) + 1e-6f);
  const float4 wv = ((const float4*)w)[tid];
  v.x = v.x * norm * wv.x;
  v.y = v.y * norm * wv.y;
  v.z = v.z * norm * wv.z;
  v.w = v.w * norm * wv.w;
  ((float4*)(io + (long)row * 1024))[tid] = v;
}

// ---------------------------------------------------------------------------
extern "C" void kernel_launch(void* const* d_in, const int* in_sizes, int n_in,
                              void* d_out, int out_size, void* d_ws, size_t ws_size,
                              hipStream_t stream) {
  (void)in_sizes; (void)n_in; (void)out_size; (void)ws_size;
  const float* xf = (const float*)d_in[0];
  const float* wqkv_f[4] = {(const float*)d_in[1], (const float*)d_in[3],
                            (const float*)d_in[5], (const float*)d_in[7]};
  const float* wo_f[4] = {(const float*)d_in[2], (const float*)d_in[4],
                          (const float*)d_in[6], (const float*)d_in[8]};
  const float* wgate_f = (const float*)d_in[9];
  const float* bgate_f = (const float*)d_in[10];
  const float* wout_f = (const float*)d_in[11];
  const float* normw_f = (const float*)d_in[12];

  char* ws = (char*)d_ws;
  bf16_t* x_c    = (bf16_t*)(ws);                 // 8 MB   [phase 1]
  bf16_t* wq_c   = (bf16_t*)(ws + (8l << 20));    // 6 MB   [phase 1, per dir]
  bf16_t* qkv    = (bf16_t*)(ws + (14l << 20));   // 24 MB  [phase 1]
  bf16_t* y      = (bf16_t*)(ws + (38l << 20));   // 32 MB  [phases 1-3]
  bf16_t* concat = (bf16_t*)(ws + (70l << 20));   // 32 MB  [phases 2-3]
  bf16_t* wo_c   = (bf16_t*)(ws);                 // 8 MB   [phase 2, reuse]
  bf16_t* wg_c   = (bf16_t*)(ws);                 // 32 MB  [phase 3, reuse]
  bf16_t* wout_c = (bf16_t*)(ws);                 // 8 MB   [phase 4, reuse]
  bf16_t* gated  = y;
  float*  fused  = (float*)d_out;                 // fp32, rmsnorm in-place

  const dim3 blk(256);
  cvt_k<<<dim3(2048), blk, 0, stream>>>(xf, x_c, 4194304 / 8);

  for (int d = 0; d < 4; d++) {
    cvt_k<<<dim3(1536), blk, 0, stream>>>(wqkv_f[d], wq_c, 3145728 / 8);
    Ptr4 bq{{wq_c, wq_c, wq_c, wq_c}};
    gemm_bt<0><<<dim3(24, 32, 1), blk, 0, stream>>>(
        x_c, 0, 1024, bq, 1024, qkv, 0, 3072, 1024, nullptr, nullptr, nullptr);
    attn_k<<<dim3(16, 64, 1), blk, 0, stream>>>(qkv, y + (long)d * 4096 * 1024, d);
  }
  {  // out-proj, z-batched over dirs -> concat[:, z*1024:(z+1)*1024]
    for (int z = 0; z < 4; z++)
      cvt_k<<<dim3(512), blk, 0, stream>>>(wo_f[z], wo_c + (long)z * 1048576,
                                           1048576 / 8);
    Ptr4 b4{{wo_c, wo_c + 1048576, wo_c + 2097152, wo_c + 3145728}};
    gemm_bt<0><<<dim3(8, 32, 4), blk, 0, stream>>>(
        y, (long)4096 * 1024, 1024, b4, 1024, concat, 1024, 4096, 1024,
        nullptr, nullptr, nullptr);
  }
  {  // gated = sigmoid(concat@wg^T + b) * concat
    cvt_k<<<dim3(8192), blk, 0, stream>>>(wgate_f, wg_c, 16777216 / 8);
    Ptr4 b4{{wg_c, wg_c, wg_c, wg_c}};
    gemm_bt<1><<<dim3(32, 32, 1), blk, 0, stream>>>(
        concat, 0, 4096, b4, 4096, gated, 0, 4096, 4096, bgate_f, concat, nullptr);
  }
  {  // fused = gated@w_out^T + x  (fp32, into d_out)
    cvt_k<<<dim3(2048), blk, 0, stream>>>(wout_f, wout_c, 4194304 / 8);
    Ptr4 b4{{wout_c, wout_c, wout_c, wout_c}};
    gemm_bt<2><<<dim3(8, 32, 1), blk, 0, stream>>>(
        gated, 0, 4096, b4, 4096, fused, 0, 1024, 4096, nullptr, nullptr, xf);
  }
  rmsnorm_k<<<dim3(4096), blk, 0, stream>>>(fused, normw_f);
}

// Round 4
// 965.264 us; speedup vs baseline: 1.1376x; 1.1376x over previous
//
#include <hip/hip_runtime.h>
#include <hip/hip_bf16.h>
#include <math.h>

// ---------------------------------------------------------------------------
// MultiDirectionalGridAttention. FP32 in/out; bf16 MFMA core, fp32 accum.
// B=4, T=1024 (32x32 grid), D=1024, NH=16, hd=64.
//
// R4: 64-key attention tiles w/ 2 barriers/tile + reversed dispatch order;
// batched weight conversion (1 launch for x,wqkv*4,wo*4); split-K=2 w_out
// GEMM with reduction folded into rmsnorm. 15 launches total.
//
// ws layout (peak 96 MB), phase-overlaid:
//   [0,8)   x_c            -> (phase3+) wout_c
//   [8,32)  wq_c x4        -> (phase4)  P0/P1 split-K partials [8,40)
//   [32,56) qkv (per dir)  -> (phase3)  wg_c [32,64)
//   [56,64) wo_c x4
//   [64,96) y -> gated
//   [0,32)  concat (phase2+)
// ---------------------------------------------------------------------------

typedef __bf16 bf16_t;
typedef __bf16 bf16x8 __attribute__((ext_vector_type(8)));
typedef float  f32x4  __attribute__((ext_vector_type(4)));

#define MFMA16(a, b, c) __builtin_amdgcn_mfma_f32_16x16x32_bf16((a), (b), (c), 0, 0, 0)

__device__ __forceinline__ void async16(const bf16_t* g, bf16_t* l) {
  __builtin_amdgcn_global_load_lds((const __attribute__((address_space(1))) void*)g,
                                   (__attribute__((address_space(3))) void*)l,
                                   16, 0, 0);
}

struct Ptr4 { const bf16_t* p[4]; };

// ------------------- batched fp32 -> bf16 convert (9 segments) --------------
struct CvtDesc {
  const float* src[9];
  bf16_t* dst[9];
  int n8[9];
};

__device__ __forceinline__ void cvt8(const float* in, bf16_t* out, int i) {
  const float4 a = ((const float4*)in)[i * 2];
  const float4 b = ((const float4*)in)[i * 2 + 1];
  bf16x8 o;
  o[0] = (bf16_t)a.x; o[1] = (bf16_t)a.y; o[2] = (bf16_t)a.z; o[3] = (bf16_t)a.w;
  o[4] = (bf16_t)b.x; o[5] = (bf16_t)b.y; o[6] = (bf16_t)b.z; o[7] = (bf16_t)b.w;
  ((bf16x8*)out)[i] = o;
}

__global__ __launch_bounds__(256) void cvt9_k(CvtDesc d) {
  const int seg = blockIdx.y;
  const int i = blockIdx.x * 256 + threadIdx.x;
  if (i >= d.n8[seg]) return;
  cvt8(d.src[seg], d.dst[seg], i);
}

__global__ __launch_bounds__(256) void cvt_k(const float* __restrict__ in,
                                             bf16_t* __restrict__ out, int n8) {
  const int i = blockIdx.x * 256 + threadIdx.x;
  if (i >= n8) return;
  cvt8(in, out, i);
}

// ---------------------------------------------------------------------------
// C = A * B^T, bf16 in, fp32 acc. 128x128 tile, BK=32, 4 waves 2x2 (m97).
// MODE 0: store bf16 C (at Cv + z*sCz)
// MODE 1: g = sigmoid(acc + bias[n]); store bf16 g * gin[m][n]
// MODE 3: split-K partial: k-range [z*koff, z*koff+K), store fp32 acc at
//         Cv + z*sCz
// ---------------------------------------------------------------------------
template <int MODE>
__global__ __launch_bounds__(256) void gemm_bt(
    const bf16_t* __restrict__ A, long sAz, int lda,
    Ptr4 B4, int ldb,
    void* __restrict__ Cv, long sCz, int ldc, int K, int koff,
    const float* __restrict__ bias,
    const bf16_t* __restrict__ gin) {
  constexpr int BM = 128, BN = 128, BK = 32;
  __shared__ __align__(16) bf16_t sA[BM * BK];
  __shared__ __align__(16) bf16_t sB[BN * BK];

  const int z = blockIdx.z;
  const bf16_t* Ap = A + (long)z * sAz;
  const bf16_t* Bp = B4.p[z];
  const int tid = threadIdx.x;
  const int wave = tid >> 6, lane = tid & 63;
  const int lane15 = lane & 15, quad = lane >> 4;
  const int bm = blockIdx.y * BM, bn = blockIdx.x * BN;
  const int wm = (wave >> 1) * 64, wn = (wave & 1) * 64;

  f32x4 acc[4][4];
#pragma unroll
  for (int i = 0; i < 4; i++)
#pragma unroll
    for (int j = 0; j < 4; j++) acc[i][j] = (f32x4){0.f, 0.f, 0.f, 0.f};

  // staging: lane l -> lds byte wave*1024 + l*16 (wave-uniform + lane*16)
  const int srow = wave * 16 + (lane >> 2);
  const int skoff = (lane & 3) * 8;
  const int kz = (MODE == 3) ? z * koff : 0;
  const bf16_t* ga = Ap + (long)(bm + srow) * lda + skoff + kz;
  const bf16_t* gb = Bp + (long)(bn + srow) * ldb + skoff + kz;
  bf16_t* la = &sA[srow * BK + skoff];
  bf16_t* lb = &sB[srow * BK + skoff];

  for (int k0 = 0; k0 < K; k0 += BK) {
    __syncthreads();  // previous iteration's LDS reads complete
    async16(ga + k0, la);
    async16(ga + k0 + (long)64 * lda, la + 64 * BK);
    async16(gb + k0, lb);
    async16(gb + k0 + (long)64 * ldb, lb + 64 * BK);
    __syncthreads();  // barrier drains vmcnt: staging visible

    bf16x8 af[4], bfv[4];
#pragma unroll
    for (int i = 0; i < 4; i++)
      af[i] = *(const bf16x8*)&sA[(wm + i * 16 + lane15) * BK + quad * 8];
#pragma unroll
    for (int j = 0; j < 4; j++)
      bfv[j] = *(const bf16x8*)&sB[(wn + j * 16 + lane15) * BK + quad * 8];
#pragma unroll
    for (int i = 0; i < 4; i++)
#pragma unroll
      for (int j = 0; j < 4; j++)
        acc[i][j] = MFMA16(af[i], bfv[j], acc[i][j]);
  }

  // C/D layout: row = quad*4 + reg, col = lane15 (m89-verified)
#pragma unroll
  for (int i = 0; i < 4; i++) {
#pragma unroll
    for (int r = 0; r < 4; r++) {
      const int row = bm + wm + i * 16 + quad * 4 + r;
      const long rb = (long)row * ldc;
#pragma unroll
      for (int j = 0; j < 4; j++) {
        const int col = bn + wn + j * 16 + lane15;
        const float v = acc[i][j][r];
        if constexpr (MODE == 0) {
          ((bf16_t*)Cv + (long)z * sCz)[rb + col] = (bf16_t)v;
        } else if constexpr (MODE == 1) {
          const float g = 1.f / (1.f + __expf(-(v + bias[col])));
          ((bf16_t*)Cv)[rb + col] = (bf16_t)(g * (float)gin[rb + col]);
        } else {
          ((float*)Cv + (long)z * sCz)[rb + col] = v;
        }
      }
    }
  }
}

// ---------------------------------------------------------------------------
// Causal-order position p -> token index t.
// dir0 lr: t=p; dir1 rl: t=1023-p; dir2 td: transpose; dir3 bu: transpose(1023-p)
// ---------------------------------------------------------------------------
__device__ __forceinline__ int perm_t(int p, int dir) {
  int q = (dir & 1) ? (1023 - p) : p;
  if (dir >= 2) q = ((q & 31) << 5) | (q >> 5);
  return q;
}

// ---------------------------------------------------------------------------
// Flash attention, causal in permuted order. Block = 4 waves, wave owns 16 q
// rows (block: 64). 64-key tiles: exactly qt+1 tiles per block. 2 barriers
// per tile (sP is per-wave: lgkmcnt covers the write->read dependency).
// Heavy q-tiles dispatch first (reversed blockIdx).
// ---------------------------------------------------------------------------
__global__ __launch_bounds__(256) void attn_k(const bf16_t* __restrict__ qkv,
                                              bf16_t* __restrict__ y, int dir) {
  const int LDQ = 3072;
  const int bh = blockIdx.y;
  const int b = bh >> 4, h = bh & 15;
  const int qt = (int)(gridDim.x - 1 - blockIdx.x);  // big blocks first
  const int tid = threadIdx.x;
  const int wave = tid >> 6, lane = tid & 63;
  const int lane15 = lane & 15, quad = lane >> 4;
  const int hoff = h * 64;
  const bf16_t* base = qkv + (long)b * 1024 * LDQ;

  __shared__ __align__(16) bf16_t sK[64 * 64];   // K tile, natural (key, d)
  __shared__ __align__(16) bf16_t sVt[64 * 72];  // V^T (d, key), 144B rows
  __shared__ __align__(16) bf16_t sP[4][16 * 64];  // per-wave P scratch

  // Q fragments (A-operand: A[m=lane15][k=quad*8+j]), live in regs whole loop
  const int qrow = qt * 64 + wave * 16 + lane15;
  const int qtok = perm_t(qrow, dir);
  const bf16x8 qa0 = *(const bf16x8*)(base + (long)qtok * LDQ + hoff + quad * 8);
  const bf16x8 qa1 = *(const bf16x8*)(base + (long)qtok * LDQ + hoff + 32 + quad * 8);

  const int qrow_c = qt * 64 + wave * 16 + quad * 4;  // + r = C-layout row

  const float FNEG = -1e30f;  // finite sentinel
  float mrow[4] = {FNEG, FNEG, FNEG, FNEG};
  float lrow[4] = {0.f, 0.f, 0.f, 0.f};
  f32x4 o[4];
#pragma unroll
  for (int d = 0; d < 4; d++) o[d] = (f32x4){0.f, 0.f, 0.f, 0.f};

  // staging coords: K: 32 rows/pass x 8 lanes (16B); V: 32 rows/pass transposed
  const int krow = tid >> 3;           // 0..31
  const int kd = (tid & 7) * 8;
  const int vj = tid & 31, vd0 = (tid >> 5) * 8;

  const int ktiles = qt + 1;
  for (int kt = 0; kt < ktiles; kt++) {
    const int kbase = kt * 64;
    const bf16x8 k0v =
        *(const bf16x8*)(base + (long)perm_t(kbase + krow, dir) * LDQ + 1024 + hoff + kd);
    const bf16x8 k1v =
        *(const bf16x8*)(base + (long)perm_t(kbase + 32 + krow, dir) * LDQ + 1024 + hoff + kd);
    const bf16x8 v0 =
        *(const bf16x8*)(base + (long)perm_t(kbase + vj, dir) * LDQ + 2048 + hoff + vd0);
    const bf16x8 v1 =
        *(const bf16x8*)(base + (long)perm_t(kbase + 32 + vj, dir) * LDQ + 2048 + hoff + vd0);
    *(bf16x8*)&sK[krow * 64 + kd] = k0v;
    *(bf16x8*)&sK[(krow + 32) * 64 + kd] = k1v;
#pragma unroll
    for (int i = 0; i < 8; i++) sVt[(vd0 + i) * 72 + vj] = v0[i];
#pragma unroll
    for (int i = 0; i < 8; i++) sVt[(vd0 + i) * 72 + 32 + vj] = v1[i];
    __syncthreads();

    // S = Q K^T (16q x 64k), four C-frags
    f32x4 s[4];
#pragma unroll
    for (int ns = 0; ns < 4; ns++) {
      const bf16x8 kb0 = *(const bf16x8*)&sK[(ns * 16 + lane15) * 64 + quad * 8];
      const bf16x8 kb1 = *(const bf16x8*)&sK[(ns * 16 + lane15) * 64 + 32 + quad * 8];
      f32x4 t = (f32x4){0.f, 0.f, 0.f, 0.f};
      t = MFMA16(qa0, kb0, t);
      t = MFMA16(qa1, kb1, t);
      s[ns] = t;
    }
    // scale + causal mask (key kp visible iff kp <= q row)
#pragma unroll
    for (int ns = 0; ns < 4; ns++) {
      const int kp = kbase + ns * 16 + lane15;
#pragma unroll
      for (int r = 0; r < 4; r++) {
        const float v = s[ns][r] * 0.125f;
        s[ns][r] = (kp <= qrow_c + r) ? v : FNEG;
      }
    }
    // row max over 64 keys (16-lane groups hold cols; 4-step butterfly)
    float tm[4];
#pragma unroll
    for (int r = 0; r < 4; r++)
      tm[r] = fmaxf(fmaxf(s[0][r], s[1][r]), fmaxf(s[2][r], s[3][r]));
#pragma unroll
    for (int off = 8; off >= 1; off >>= 1)
#pragma unroll
      for (int r = 0; r < 4; r++) tm[r] = fmaxf(tm[r], __shfl_xor(tm[r], off));

    float alpha[4];
#pragma unroll
    for (int r = 0; r < 4; r++) {
      const float mn = fmaxf(mrow[r], tm[r]);
      alpha[r] = __expf(mrow[r] - mn);
      mrow[r] = mn;
    }
    float ps[4][4];
#pragma unroll
    for (int ns = 0; ns < 4; ns++)
#pragma unroll
      for (int r = 0; r < 4; r++) ps[ns][r] = __expf(s[ns][r] - mrow[r]);
    float ts[4];
#pragma unroll
    for (int r = 0; r < 4; r++)
      ts[r] = (ps[0][r] + ps[1][r]) + (ps[2][r] + ps[3][r]);
#pragma unroll
    for (int off = 8; off >= 1; off >>= 1)
#pragma unroll
      for (int r = 0; r < 4; r++) ts[r] += __shfl_xor(ts[r], off);
#pragma unroll
    for (int r = 0; r < 4; r++) lrow[r] = lrow[r] * alpha[r] + ts[r];
#pragma unroll
    for (int d = 0; d < 4; d++)
#pragma unroll
      for (int r = 0; r < 4; r++) o[d][r] *= alpha[r];

    // P: C-layout -> bf16 A-layout via per-wave LDS scratch (lgkmcnt sync only)
#pragma unroll
    for (int ns = 0; ns < 4; ns++)
#pragma unroll
      for (int r = 0; r < 4; r++)
        sP[wave][(quad * 4 + r) * 64 + ns * 16 + lane15] = (bf16_t)ps[ns][r];

    const bf16x8 pa0 = *(const bf16x8*)&sP[wave][lane15 * 64 + quad * 8];
    const bf16x8 pa1 = *(const bf16x8*)&sP[wave][lane15 * 64 + 32 + quad * 8];
#pragma unroll
    for (int d = 0; d < 4; d++) {
      const bf16x8 vb0 = *(const bf16x8*)&sVt[(d * 16 + lane15) * 72 + quad * 8];
      const bf16x8 vb1 = *(const bf16x8*)&sVt[(d * 16 + lane15) * 72 + 32 + quad * 8];
      o[d] = MFMA16(pa0, vb0, o[d]);
      o[d] = MFMA16(pa1, vb1, o[d]);
    }
    __syncthreads();  // all sK/sVt reads done before next tile's staging
  }

  // epilogue: O / l, scatter rows back to token order
#pragma unroll
  for (int r = 0; r < 4; r++) {
    const float rinv = 1.f / fmaxf(lrow[r], 1e-20f);
    const int tok = perm_t(qrow_c + r, dir);
    bf16_t* yrow = y + ((long)b * 1024 + tok) * 1024 + hoff;
#pragma unroll
    for (int d = 0; d < 4; d++) yrow[d * 16 + lane15] = (bf16_t)(o[d][r] * rinv);
  }
}

// ---------------------------------------------------------------------------
// RMSNorm over rows of 1024: v = P0 + P1 + x (split-K reduce + residual),
// out = v * rsqrt(mean(v^2)+eps) * w. fp32 end-to-end (matches reference).
// ---------------------------------------------------------------------------
__global__ __launch_bounds__(256) void rmsnorm_k(const float* __restrict__ p0,
                                                 const float* __restrict__ p1,
                                                 const float* __restrict__ x,
                                                 const float* __restrict__ w,
                                                 float* __restrict__ out) {
  const int row = blockIdx.x, tid = threadIdx.x;
  const long off = (long)row * 1024;
  const float4 a = ((const float4*)(p0 + off))[tid];
  const float4 bq = ((const float4*)(p1 + off))[tid];
  const float4 c = ((const float4*)(x + off))[tid];
  float4 v;
  v.x = a.x + bq.x + c.x;
  v.y = a.y + bq.y + c.y;
  v.z = a.z + bq.z + c.z;
  v.w = a.w + bq.w + c.w;
  float ss = v.x * v.x + v.y * v.y + v.z * v.z + v.w * v.w;
#pragma unroll
  for (int o2 = 32; o2 >= 1; o2 >>= 1) ss += __shfl_xor(ss, o2);
  __shared__ float wsum[4];
  if ((tid & 63) == 0) wsum[tid >> 6] = ss;
  __syncthreads();
  const float tot = wsum[0] + wsum[1] + wsum[2] + wsum[3];
  const float norm = rsqrtf(tot * (1.f / 1024.f) + 1e-6f);
  const float4 wv = ((const float4*)w)[tid];
  v.x = v.x * norm * wv.x;
  v.y = v.y * norm * wv.y;
  v.z = v.z * norm * wv.z;
  v.w = v.w * norm * wv.w;
  ((float4*)(out + off))[tid] = v;
}

// ---------------------------------------------------------------------------
extern "C" void kernel_launch(void* const* d_in, const int* in_sizes, int n_in,
                              void* d_out, int out_size, void* d_ws, size_t ws_size,
                              hipStream_t stream) {
  (void)in_sizes; (void)n_in; (void)out_size; (void)ws_size;
  const float* xf = (const float*)d_in[0];
  const float* wqkv_f[4] = {(const float*)d_in[1], (const float*)d_in[3],
                            (const float*)d_in[5], (const float*)d_in[7]};
  const float* wo_f[4] = {(const float*)d_in[2], (const float*)d_in[4],
                          (const float*)d_in[6], (const float*)d_in[8]};
  const float* wgate_f = (const float*)d_in[9];
  const float* bgate_f = (const float*)d_in[10];
  const float* wout_f = (const float*)d_in[11];
  const float* normw_f = (const float*)d_in[12];

  const long MB = 1l << 20;
  char* ws = (char*)d_ws;
  bf16_t* x_c    = (bf16_t*)(ws);             // 8 MB
  bf16_t* wq_c   = (bf16_t*)(ws + 8 * MB);    // 24 MB (4 dirs)
  bf16_t* qkv    = (bf16_t*)(ws + 32 * MB);   // 24 MB (per-dir reuse)
  bf16_t* wo_c   = (bf16_t*)(ws + 56 * MB);   // 8 MB (4 dirs)
  bf16_t* y      = (bf16_t*)(ws + 64 * MB);   // 32 MB -> gated
  bf16_t* concat = (bf16_t*)(ws);             // 32 MB (phase 2+)
  bf16_t* wg_c   = (bf16_t*)(ws + 32 * MB);   // 32 MB (phase 3)
  bf16_t* wout_c = (bf16_t*)(ws);             // 8 MB (phase 4)
  float*  part   = (float*)(ws + 8 * MB);     // 2x16 MB split-K partials
  bf16_t* gated  = y;

  const dim3 blk(256);

  {  // one batched conversion: x, wqkv x4, wo x4
    CvtDesc cd;
    cd.src[0] = xf; cd.dst[0] = x_c; cd.n8[0] = 4194304 / 8;
    for (int d = 0; d < 4; d++) {
      cd.src[1 + d] = wqkv_f[d];
      cd.dst[1 + d] = wq_c + (long)d * 3145728;
      cd.n8[1 + d] = 3145728 / 8;
      cd.src[5 + d] = wo_f[d];
      cd.dst[5 + d] = wo_c + (long)d * 1048576;
      cd.n8[5 + d] = 1048576 / 8;
    }
    cvt9_k<<<dim3(2048, 9), blk, 0, stream>>>(cd);
  }

  for (int d = 0; d < 4; d++) {
    const bf16_t* wq_d = wq_c + (long)d * 3145728;
    Ptr4 bq{{wq_d, wq_d, wq_d, wq_d}};
    gemm_bt<0><<<dim3(24, 32, 1), blk, 0, stream>>>(
        x_c, 0, 1024, bq, 1024, qkv, 0, 3072, 1024, 0, nullptr, nullptr);
    attn_k<<<dim3(16, 64, 1), blk, 0, stream>>>(qkv, y + (long)d * 4096 * 1024, d);
  }
  {  // out-proj, z-batched over dirs -> concat[:, z*1024:(z+1)*1024]
    Ptr4 b4{{wo_c, wo_c + 1048576, wo_c + 2097152, wo_c + 3145728}};
    gemm_bt<0><<<dim3(8, 32, 4), blk, 0, stream>>>(
        y, (long)4096 * 1024, 1024, b4, 1024, concat, 1024, 4096, 1024, 0,
        nullptr, nullptr);
  }
  {  // gated = sigmoid(concat@wg^T + b) * concat
    cvt_k<<<dim3(8192), blk, 0, stream>>>(wgate_f, wg_c, 16777216 / 8);
    Ptr4 b4{{wg_c, wg_c, wg_c, wg_c}};
    gemm_bt<1><<<dim3(32, 32, 1), blk, 0, stream>>>(
        concat, 0, 4096, b4, 4096, gated, 0, 4096, 4096, 0, bgate_f, concat);
  }
  {  // split-K=2: part[z] = gated[:, z*2048:(z+1)*2048] @ wout[:, same]^T
    cvt_k<<<dim3(2048), blk, 0, stream>>>(wout_f, wout_c, 4194304 / 8);
    Ptr4 b4{{wout_c, wout_c, wout_c, wout_c}};
    gemm_bt<3><<<dim3(8, 32, 2), blk, 0, stream>>>(
        gated, 0, 4096, b4, 4096, part, (long)4096 * 1024, 1024, 2048, 2048,
        nullptr, nullptr);
  }
  rmsnorm_k<<<dim3(4096), blk, 0, stream>>>(part, part + (long)4096 * 1024, xf,
                                            normw_f, (float*)d_out);
}

// Round 5
// 946.568 us; speedup vs baseline: 1.1601x; 1.0198x over previous
//
#include <hip/hip_runtime.h>
#include <hip/hip_bf16.h>
#include <math.h>

// ---------------------------------------------------------------------------
// MultiDirectionalGridAttention. FP32 in/out; bf16 MFMA core, fp32 accum.
// B=4, T=1024 (32x32 grid), D=1024, NH=16, hd=64.
//
// R5: (1) vectorized GEMM epilogue via padded-LDS round-trip (was 128 scalar
// global ops/thread); (2) ws_size-guarded fully-batched phase 1 (one z=4 qkv
// GEMM + one 4-dir attention launch); (3) batched wgate/wout conversion.
//
// Batched ws layout (168 MB peak), phase-overlaid:
//   [0,8)    x_c         -> (phase2+) concat [0,32)
//   [8,32)   wq_c x4
//   [32,40)  wo_c x4
//   [40,136) qkv_all     -> (phase3) wg_c [40,72), wout_c [72,80), part [80,112)
//   [136,168) y -> gated
// Fallback (<168 MB): R4's 96 MB per-dir layout.
// ---------------------------------------------------------------------------

typedef __bf16 bf16_t;
typedef __bf16 bf16x4 __attribute__((ext_vector_type(4)));
typedef __bf16 bf16x8 __attribute__((ext_vector_type(8)));
typedef float  f32x4  __attribute__((ext_vector_type(4)));

#define MFMA16(a, b, c) __builtin_amdgcn_mfma_f32_16x16x32_bf16((a), (b), (c), 0, 0, 0)

__device__ __forceinline__ void async16(const bf16_t* g, bf16_t* l) {
  __builtin_amdgcn_global_load_lds((const __attribute__((address_space(1))) void*)g,
                                   (__attribute__((address_space(3))) void*)l,
                                   16, 0, 0);
}

struct Ptr4 { const bf16_t* p[4]; };

// ------------------- batched fp32 -> bf16 convert (<=9 segments) ------------
struct CvtDesc {
  const float* src[9];
  bf16_t* dst[9];
  int n8[9];
};

__device__ __forceinline__ void cvt8(const float* in, bf16_t* out, int i) {
  const float4 a = ((const float4*)in)[i * 2];
  const float4 b = ((const float4*)in)[i * 2 + 1];
  bf16x8 o;
  o[0] = (bf16_t)a.x; o[1] = (bf16_t)a.y; o[2] = (bf16_t)a.z; o[3] = (bf16_t)a.w;
  o[4] = (bf16_t)b.x; o[5] = (bf16_t)b.y; o[6] = (bf16_t)b.z; o[7] = (bf16_t)b.w;
  ((bf16x8*)out)[i] = o;
}

__global__ __launch_bounds__(256) void cvt9_k(CvtDesc d) {
  const int seg = blockIdx.y;
  const int i = blockIdx.x * 256 + threadIdx.x;
  if (i >= d.n8[seg]) return;
  cvt8(d.src[seg], d.dst[seg], i);
}

// ---------------------------------------------------------------------------
// C = A * B^T, bf16 in, fp32 acc. 128x128 tile, BK=32, 4 waves 2x2 (m97).
// Epilogue: 2-pass fp32 LDS staging (stride 144 f32 = 2-way banks, free),
// coalesced float4 reads, vectorized stores/gin/bias.
// MODE 0: store bf16 C (at Cv + z*sCz)
// MODE 1: g = sigmoid(acc + bias[n]); store bf16 g * gin[m][n]
// MODE 3: split-K partial over k-range [z*koff, z*koff+K), fp32 C at Cv+z*sCz
// ---------------------------------------------------------------------------
template <int MODE>
__global__ __launch_bounds__(256) void gemm_bt(
    const bf16_t* __restrict__ A, long sAz, int lda,
    Ptr4 B4, int ldb,
    void* __restrict__ Cv, long sCz, int ldc, int K, int koff,
    const float* __restrict__ bias,
    const bf16_t* __restrict__ gin) {
  constexpr int BM = 128, BN = 128, BK = 32;
  __shared__ __align__(16) bf16_t sA[BM * BK];
  __shared__ __align__(16) bf16_t sB[BN * BK];
  __shared__ __align__(16) float sC[64 * 144];  // epilogue staging, 36.9 KB

  const int z = blockIdx.z;
  const bf16_t* Ap = A + (long)z * sAz;
  const bf16_t* Bp = B4.p[z];
  const int tid = threadIdx.x;
  const int wave = tid >> 6, lane = tid & 63;
  const int lane15 = lane & 15, quad = lane >> 4;
  const int bm = blockIdx.y * BM, bn = blockIdx.x * BN;
  const int wm = (wave >> 1) * 64, wn = (wave & 1) * 64;

  f32x4 acc[4][4];
#pragma unroll
  for (int i = 0; i < 4; i++)
#pragma unroll
    for (int j = 0; j < 4; j++) acc[i][j] = (f32x4){0.f, 0.f, 0.f, 0.f};

  // staging: lane l -> lds byte wave*1024 + l*16 (wave-uniform + lane*16)
  const int srow = wave * 16 + (lane >> 2);
  const int skoff = (lane & 3) * 8;
  const int kz = (MODE == 3) ? z * koff : 0;
  const bf16_t* ga = Ap + (long)(bm + srow) * lda + skoff + kz;
  const bf16_t* gb = Bp + (long)(bn + srow) * ldb + skoff + kz;
  bf16_t* la = &sA[srow * BK + skoff];
  bf16_t* lb = &sB[srow * BK + skoff];

  for (int k0 = 0; k0 < K; k0 += BK) {
    __syncthreads();  // previous iteration's LDS reads complete
    async16(ga + k0, la);
    async16(ga + k0 + (long)64 * lda, la + 64 * BK);
    async16(gb + k0, lb);
    async16(gb + k0 + (long)64 * ldb, lb + 64 * BK);
    __syncthreads();  // barrier drains vmcnt: staging visible

    bf16x8 af[4], bfv[4];
#pragma unroll
    for (int i = 0; i < 4; i++)
      af[i] = *(const bf16x8*)&sA[(wm + i * 16 + lane15) * BK + quad * 8];
#pragma unroll
    for (int j = 0; j < 4; j++)
      bfv[j] = *(const bf16x8*)&sB[(wn + j * 16 + lane15) * BK + quad * 8];
#pragma unroll
    for (int i = 0; i < 4; i++)
#pragma unroll
      for (int j = 0; j < 4; j++)
        acc[i][j] = MFMA16(af[i], bfv[j], acc[i][j]);
  }

  // Epilogue. C/D layout: row = wm + i*16 + quad*4 + r, col = wn + j*16 +
  // lane15 (m89-verified). Pass p stages i in {2p, 2p+1}: 64 rows x 128 cols.
#pragma unroll
  for (int p = 0; p < 2; p++) {
    if (p) __syncthreads();  // pass-0 reads done before overwrite
#pragma unroll
    for (int ii = 0; ii < 2; ii++) {
      const int i = 2 * p + ii;
      const int sr = (wm >> 1) + ii * 16 + quad * 4;
#pragma unroll
      for (int r = 0; r < 4; r++)
#pragma unroll
        for (int j = 0; j < 4; j++)
          sC[(sr + r) * 144 + wn + j * 16 + lane15] = acc[i][j][r];
    }
    __syncthreads();
#pragma unroll
    for (int c = 0; c < 8; c++) {
      const int idx = c * 256 + tid;
      const int srr = idx >> 5, chunk = idx & 31;
      const float4 v4 = *(const float4*)&sC[srr * 144 + chunk * 4];
      const int grow = bm + (srr & 31) + (srr >> 5) * 64 + p * 32;
      const int gcol = bn + chunk * 4;
      const long goff = (long)grow * ldc + gcol;
      if constexpr (MODE == 0) {
        bf16x4 o;
        o[0] = (bf16_t)v4.x; o[1] = (bf16_t)v4.y;
        o[2] = (bf16_t)v4.z; o[3] = (bf16_t)v4.w;
        *(bf16x4*)((bf16_t*)Cv + (long)z * sCz + goff) = o;
      } else if constexpr (MODE == 1) {
        const float4 bb = *(const float4*)&bias[gcol];
        const bf16x4 gv = *(const bf16x4*)&gin[goff];
        bf16x4 o;
        o[0] = (bf16_t)((float)gv[0] / (1.f + __expf(-(v4.x + bb.x))));
        o[1] = (bf16_t)((float)gv[1] / (1.f + __expf(-(v4.y + bb.y))));
        o[2] = (bf16_t)((float)gv[2] / (1.f + __expf(-(v4.z + bb.z))));
        o[3] = (bf16_t)((float)gv[3] / (1.f + __expf(-(v4.w + bb.w))));
        *(bf16x4*)((bf16_t*)Cv + goff) = o;
      } else {
        *(float4*)((float*)Cv + (long)z * sCz + goff) = v4;
      }
    }
  }
}

// ---------------------------------------------------------------------------
// Causal-order position p -> token index t.
// dir0 lr: t=p; dir1 rl: t=1023-p; dir2 td: transpose; dir3 bu: transpose(1023-p)
// ---------------------------------------------------------------------------
__device__ __forceinline__ int perm_t(int p, int dir) {
  int q = (dir & 1) ? (1023 - p) : p;
  if (dir >= 2) q = ((q & 31) << 5) | (q >> 5);
  return q;
}

// ---------------------------------------------------------------------------
// Flash attention, causal in permuted order. Block = 4 waves, wave owns 16 q
// rows (block: 64). 64-key tiles: exactly qt+1 tiles. 2 barriers/tile.
// blockIdx.y = zi*64 + (b*16+h); dir = dir0 + zi. Heavy q-tiles first.
// ---------------------------------------------------------------------------
__global__ __launch_bounds__(256) void attn_k(const bf16_t* __restrict__ qkv,
                                              long sQz, bf16_t* __restrict__ y,
                                              long sYz, int dir0) {
  const int LDQ = 3072;
  const int zi = blockIdx.y >> 6;
  const int bh = blockIdx.y & 63;
  const int dir = dir0 + zi;
  const int b = bh >> 4, h = bh & 15;
  const int qt = (int)(gridDim.x - 1 - blockIdx.x);  // big blocks first
  const int tid = threadIdx.x;
  const int wave = tid >> 6, lane = tid & 63;
  const int lane15 = lane & 15, quad = lane >> 4;
  const int hoff = h * 64;
  const bf16_t* base = qkv + (long)zi * sQz + (long)b * 1024 * LDQ;
  bf16_t* yd = y + (long)zi * sYz;

  __shared__ __align__(16) bf16_t sK[64 * 64];   // K tile, natural (key, d)
  __shared__ __align__(16) bf16_t sVt[64 * 72];  // V^T (d, key), 144B rows
  __shared__ __align__(16) bf16_t sP[4][16 * 64];  // per-wave P scratch

  // Q fragments (A-operand: A[m=lane15][k=quad*8+j]), live in regs whole loop
  const int qrow = qt * 64 + wave * 16 + lane15;
  const int qtok = perm_t(qrow, dir);
  const bf16x8 qa0 = *(const bf16x8*)(base + (long)qtok * LDQ + hoff + quad * 8);
  const bf16x8 qa1 = *(const bf16x8*)(base + (long)qtok * LDQ + hoff + 32 + quad * 8);

  const int qrow_c = qt * 64 + wave * 16 + quad * 4;  // + r = C-layout row

  const float FNEG = -1e30f;  // finite sentinel
  float mrow[4] = {FNEG, FNEG, FNEG, FNEG};
  float lrow[4] = {0.f, 0.f, 0.f, 0.f};
  f32x4 o[4];
#pragma unroll
  for (int d = 0; d < 4; d++) o[d] = (f32x4){0.f, 0.f, 0.f, 0.f};

  const int krow = tid >> 3;  // 0..31
  const int kd = (tid & 7) * 8;
  const int vj = tid & 31, vd0 = (tid >> 5) * 8;

  const int ktiles = qt + 1;
  for (int kt = 0; kt < ktiles; kt++) {
    const int kbase = kt * 64;
    const bf16x8 k0v =
        *(const bf16x8*)(base + (long)perm_t(kbase + krow, dir) * LDQ + 1024 + hoff + kd);
    const bf16x8 k1v =
        *(const bf16x8*)(base + (long)perm_t(kbase + 32 + krow, dir) * LDQ + 1024 + hoff + kd);
    const bf16x8 v0 =
        *(const bf16x8*)(base + (long)perm_t(kbase + vj, dir) * LDQ + 2048 + hoff + vd0);
    const bf16x8 v1 =
        *(const bf16x8*)(base + (long)perm_t(kbase + 32 + vj, dir) * LDQ + 2048 + hoff + vd0);
    *(bf16x8*)&sK[krow * 64 + kd] = k0v;
    *(bf16x8*)&sK[(krow + 32) * 64 + kd] = k1v;
#pragma unroll
    for (int i = 0; i < 8; i++) sVt[(vd0 + i) * 72 + vj] = v0[i];
#pragma unroll
    for (int i = 0; i < 8; i++) sVt[(vd0 + i) * 72 + 32 + vj] = v1[i];
    __syncthreads();

    // S = Q K^T (16q x 64k), four C-frags
    f32x4 s[4];
#pragma unroll
    for (int ns = 0; ns < 4; ns++) {
      const bf16x8 kb0 = *(const bf16x8*)&sK[(ns * 16 + lane15) * 64 + quad * 8];
      const bf16x8 kb1 = *(const bf16x8*)&sK[(ns * 16 + lane15) * 64 + 32 + quad * 8];
      f32x4 t = (f32x4){0.f, 0.f, 0.f, 0.f};
      t = MFMA16(qa0, kb0, t);
      t = MFMA16(qa1, kb1, t);
      s[ns] = t;
    }
    // scale + causal mask (key kp visible iff kp <= q row)
#pragma unroll
    for (int ns = 0; ns < 4; ns++) {
      const int kp = kbase + ns * 16 + lane15;
#pragma unroll
      for (int r = 0; r < 4; r++) {
        const float v = s[ns][r] * 0.125f;
        s[ns][r] = (kp <= qrow_c + r) ? v : FNEG;
      }
    }
    // row max over 64 keys (16-lane groups hold cols)
    float tm[4];
#pragma unroll
    for (int r = 0; r < 4; r++)
      tm[r] = fmaxf(fmaxf(s[0][r], s[1][r]), fmaxf(s[2][r], s[3][r]));
#pragma unroll
    for (int off = 8; off >= 1; off >>= 1)
#pragma unroll
      for (int r = 0; r < 4; r++) tm[r] = fmaxf(tm[r], __shfl_xor(tm[r], off));

    float alpha[4];
#pragma unroll
    for (int r = 0; r < 4; r++) {
      const float mn = fmaxf(mrow[r], tm[r]);
      alpha[r] = __expf(mrow[r] - mn);
      mrow[r] = mn;
    }
    float ps[4][4];
#pragma unroll
    for (int ns = 0; ns < 4; ns++)
#pragma unroll
      for (int r = 0; r < 4; r++) ps[ns][r] = __expf(s[ns][r] - mrow[r]);
    float ts[4];
#pragma unroll
    for (int r = 0; r < 4; r++)
      ts[r] = (ps[0][r] + ps[1][r]) + (ps[2][r] + ps[3][r]);
#pragma unroll
    for (int off = 8; off >= 1; off >>= 1)
#pragma unroll
      for (int r = 0; r < 4; r++) ts[r] += __shfl_xor(ts[r], off);
#pragma unroll
    for (int r = 0; r < 4; r++) lrow[r] = lrow[r] * alpha[r] + ts[r];
#pragma unroll
    for (int d = 0; d < 4; d++)
#pragma unroll
      for (int r = 0; r < 4; r++) o[d][r] *= alpha[r];

    // P: C-layout -> bf16 A-layout via per-wave LDS scratch (lgkmcnt sync only)
#pragma unroll
    for (int ns = 0; ns < 4; ns++)
#pragma unroll
      for (int r = 0; r < 4; r++)
        sP[wave][(quad * 4 + r) * 64 + ns * 16 + lane15] = (bf16_t)ps[ns][r];

    const bf16x8 pa0 = *(const bf16x8*)&sP[wave][lane15 * 64 + quad * 8];
    const bf16x8 pa1 = *(const bf16x8*)&sP[wave][lane15 * 64 + 32 + quad * 8];
#pragma unroll
    for (int d = 0; d < 4; d++) {
      const bf16x8 vb0 = *(const bf16x8*)&sVt[(d * 16 + lane15) * 72 + quad * 8];
      const bf16x8 vb1 = *(const bf16x8*)&sVt[(d * 16 + lane15) * 72 + 32 + quad * 8];
      o[d] = MFMA16(pa0, vb0, o[d]);
      o[d] = MFMA16(pa1, vb1, o[d]);
    }
    __syncthreads();  // all sK/sVt reads done before next tile's staging
  }

  // epilogue: O / l, scatter rows back to token order
#pragma unroll
  for (int r = 0; r < 4; r++) {
    const float rinv = 1.f / fmaxf(lrow[r], 1e-20f);
    const int tok = perm_t(qrow_c + r, dir);
    bf16_t* yrow = yd + ((long)b * 1024 + tok) * 1024 + hoff;
#pragma unroll
    for (int d = 0; d < 4; d++) yrow[d * 16 + lane15] = (bf16_t)(o[d][r] * rinv);
  }
}

// ---------------------------------------------------------------------------
// RMSNorm over rows of 1024: v = P0 + P1 + x (split-K reduce + residual).
// ---------------------------------------------------------------------------
__global__ __launch_bounds__(256) void rmsnorm_k(const float* __restrict__ p0,
                                                 const float* __restrict__ p1,
                                                 const float* __restrict__ x,
                                                 const float* __restrict__ w,
                                                 float* __restrict__ out) {
  const int row = blockIdx.x, tid = threadIdx.x;
  const long off = (long)row * 1024;
  const float4 a = ((const float4*)(p0 + off))[tid];
  const float4 bq = ((const float4*)(p1 + off))[tid];
  const float4 c = ((const float4*)(x + off))[tid];
  float4 v;
  v.x = a.x + bq.x + c.x;
  v.y = a.y + bq.y + c.y;
  v.z = a.z + bq.z + c.z;
  v.w = a.w + bq.w + c.w;
  float ss = v.x * v.x + v.y * v.y + v.z * v.z + v.w * v.w;
#pragma unroll
  for (int o2 = 32; o2 >= 1; o2 >>= 1) ss += __shfl_xor(ss, o2);
  __shared__ float wsum[4];
  if ((tid & 63) == 0) wsum[tid >> 6] = ss;
  __syncthreads();
  const float tot = wsum[0] + wsum[1] + wsum[2] + wsum[3];
  const float norm = rsqrtf(tot * (1.f / 1024.f) + 1e-6f);
  const float4 wv = ((const float4*)w)[tid];
  v.x = v.x * norm * wv.x;
  v.y = v.y * norm * wv.y;
  v.z = v.z * norm * wv.z;
  v.w = v.w * norm * wv.w;
  ((float4*)(out + off))[tid] = v;
}

// ---------------------------------------------------------------------------
extern "C" void kernel_launch(void* const* d_in, const int* in_sizes, int n_in,
                              void* d_out, int out_size, void* d_ws, size_t ws_size,
                              hipStream_t stream) {
  (void)in_sizes; (void)n_in; (void)out_size;
  const float* xf = (const float*)d_in[0];
  const float* wqkv_f[4] = {(const float*)d_in[1], (const float*)d_in[3],
                            (const float*)d_in[5], (const float*)d_in[7]};
  const float* wo_f[4] = {(const float*)d_in[2], (const float*)d_in[4],
                          (const float*)d_in[6], (const float*)d_in[8]};
  const float* wgate_f = (const float*)d_in[9];
  const float* bgate_f = (const float*)d_in[10];
  const float* wout_f = (const float*)d_in[11];
  const float* normw_f = (const float*)d_in[12];

  const long MB = 1l << 20;
  char* ws = (char*)d_ws;
  const dim3 blk(256);
  const bool batched = ws_size >= (size_t)(168 * MB);

  if (batched) {
    bf16_t* x_c    = (bf16_t*)(ws);              // 8 MB
    bf16_t* wq_c   = (bf16_t*)(ws + 8 * MB);     // 24 MB
    bf16_t* wo_c   = (bf16_t*)(ws + 32 * MB);    // 8 MB
    bf16_t* qkv    = (bf16_t*)(ws + 40 * MB);    // 96 MB (4 dirs)
    bf16_t* y      = (bf16_t*)(ws + 136 * MB);   // 32 MB -> gated
    bf16_t* concat = (bf16_t*)(ws);              // 32 MB (phase 2+)
    bf16_t* wg_c   = (bf16_t*)(ws + 40 * MB);    // 32 MB (phase 3)
    bf16_t* wout_c = (bf16_t*)(ws + 72 * MB);    // 8 MB
    float*  part   = (float*)(ws + 80 * MB);     // 2x16 MB split-K partials
    bf16_t* gated  = y;

    {  // batched conversion: x, wqkv x4, wo x4
      CvtDesc cd;
      cd.src[0] = xf; cd.dst[0] = x_c; cd.n8[0] = 4194304 / 8;
      for (int d = 0; d < 4; d++) {
        cd.src[1 + d] = wqkv_f[d];
        cd.dst[1 + d] = wq_c + (long)d * 3145728;
        cd.n8[1 + d] = 3145728 / 8;
        cd.src[5 + d] = wo_f[d];
        cd.dst[5 + d] = wo_c + (long)d * 1048576;
        cd.n8[5 + d] = 1048576 / 8;
      }
      cvt9_k<<<dim3(2048, 9), blk, 0, stream>>>(cd);
    }
    {  // all 4 qkv GEMMs in one launch
      Ptr4 bq{{wq_c, wq_c + 3145728, wq_c + 2l * 3145728, wq_c + 3l * 3145728}};
      gemm_bt<0><<<dim3(24, 32, 4), blk, 0, stream>>>(
          x_c, 0, 1024, bq, 1024, qkv, (long)4096 * 3072, 3072, 1024, 0,
          nullptr, nullptr);
    }
    // all 4 attentions in one launch
    attn_k<<<dim3(16, 256), blk, 0, stream>>>(qkv, (long)4096 * 3072, y,
                                              (long)4096 * 1024, 0);
    {  // out-proj, z-batched -> concat[:, z*1024:(z+1)*1024]
      Ptr4 b4{{wo_c, wo_c + 1048576, wo_c + 2097152, wo_c + 3145728}};
      gemm_bt<0><<<dim3(8, 32, 4), blk, 0, stream>>>(
          y, (long)4096 * 1024, 1024, b4, 1024, concat, 1024, 4096, 1024, 0,
          nullptr, nullptr);
    }
    {  // convert wgate + wout
      CvtDesc cd;
      for (int s = 0; s < 9; s++) cd.n8[s] = 0;
      cd.src[0] = wgate_f; cd.dst[0] = wg_c; cd.n8[0] = 16777216 / 8;
      cd.src[1] = wout_f; cd.dst[1] = wout_c; cd.n8[1] = 4194304 / 8;
      cvt9_k<<<dim3(8192, 2), blk, 0, stream>>>(cd);
    }
    {  // gated = sigmoid(concat@wg^T + b) * concat
      Ptr4 b4{{wg_c, wg_c, wg_c, wg_c}};
      gemm_bt<1><<<dim3(32, 32, 1), blk, 0, stream>>>(
          concat, 0, 4096, b4, 4096, gated, 0, 4096, 4096, 0, bgate_f, concat);
    }
    {  // split-K=2 w_out partials
      Ptr4 b4{{wout_c, wout_c, wout_c, wout_c}};
      gemm_bt<3><<<dim3(8, 32, 2), blk, 0, stream>>>(
          gated, 0, 4096, b4, 4096, part, (long)4096 * 1024, 1024, 2048, 2048,
          nullptr, nullptr);
    }
    rmsnorm_k<<<dim3(4096), blk, 0, stream>>>(part, part + (long)4096 * 1024,
                                              xf, normw_f, (float*)d_out);
  } else {
    // fallback: per-dir qkv+attention (96 MB peak), R4 layout
    bf16_t* x_c    = (bf16_t*)(ws);             // 8 MB
    bf16_t* wq_c   = (bf16_t*)(ws + 8 * MB);    // 24 MB
    bf16_t* qkv    = (bf16_t*)(ws + 32 * MB);   // 24 MB (per-dir reuse)
    bf16_t* wo_c   = (bf16_t*)(ws + 56 * MB);   // 8 MB
    bf16_t* y      = (bf16_t*)(ws + 64 * MB);   // 32 MB -> gated
    bf16_t* concat = (bf16_t*)(ws);             // 32 MB (phase 2+)
    bf16_t* wg_c   = (bf16_t*)(ws + 32 * MB);   // 32 MB (phase 3)
    bf16_t* wout_c = (bf16_t*)(ws);             // 8 MB (phase 4)
    float*  part   = (float*)(ws + 8 * MB);     // 2x16 MB
    bf16_t* gated  = y;

    {
      CvtDesc cd;
      cd.src[0] = xf; cd.dst[0] = x_c; cd.n8[0] = 4194304 / 8;
      for (int d = 0; d < 4; d++) {
        cd.src[1 + d] = wqkv_f[d];
        cd.dst[1 + d] = wq_c + (long)d * 3145728;
        cd.n8[1 + d] = 3145728 / 8;
        cd.src[5 + d] = wo_f[d];
        cd.dst[5 + d] = wo_c + (long)d * 1048576;
        cd.n8[5 + d] = 1048576 / 8;
      }
      cvt9_k<<<dim3(2048, 9), blk, 0, stream>>>(cd);
    }
    for (int d = 0; d < 4; d++) {
      const bf16_t* wq_d = wq_c + (long)d * 3145728;
      Ptr4 bq{{wq_d, wq_d, wq_d, wq_d}};
      gemm_bt<0><<<dim3(24, 32, 1), blk, 0, stream>>>(
          x_c, 0, 1024, bq, 1024, qkv, 0, 3072, 1024, 0, nullptr, nullptr);
      attn_k<<<dim3(16, 64), blk, 0, stream>>>(qkv, 0, y + (long)d * 4194304,
                                               0, d);
    }
    {
      Ptr4 b4{{wo_c, wo_c + 1048576, wo_c + 2097152, wo_c + 3145728}};
      gemm_bt<0><<<dim3(8, 32, 4), blk, 0, stream>>>(
          y, (long)4096 * 1024, 1024, b4, 1024, concat, 1024, 4096, 1024, 0,
          nullptr, nullptr);
    }
    {
      CvtDesc cd;
      for (int s = 0; s < 9; s++) cd.n8[s] = 0;
      cd.src[0] = wgate_f; cd.dst[0] = wg_c; cd.n8[0] = 16777216 / 8;
      cd.src[1] = wout_f; cd.dst[1] = wout_c; cd.n8[1] = 4194304 / 8;
      cvt9_k<<<dim3(8192, 2), blk, 0, stream>>>(cd);
    }
    {
      Ptr4 b4{{wg_c, wg_c, wg_c, wg_c}};
      gemm_bt<1><<<dim3(32, 32, 1), blk, 0, stream>>>(
          concat, 0, 4096, b4, 4096, gated, 0, 4096, 4096, 0, bgate_f, concat);
    }
    {
      Ptr4 b4{{wout_c, wout_c, wout_c, wout_c}};
      gemm_bt<3><<<dim3(8, 32, 2), blk, 0, stream>>>(
          gated, 0, 4096, b4, 4096, part, (long)4096 * 1024, 1024, 2048, 2048,
          nullptr, nullptr);
    }
    rmsnorm_k<<<dim3(4096), blk, 0, stream>>>(part, part + (long)4096 * 1024,
                                              xf, normw_f, (float*)d_out);
  }
}

// Round 7
// 858.774 us; speedup vs baseline: 1.2787x; 1.1022x over previous
//
#include <hip/hip_runtime.h>
#include <hip/hip_bf16.h>
#include <math.h>

// ---------------------------------------------------------------------------
// MultiDirectionalGridAttention. FP32 in/out; bf16 MFMA core, fp32 accum.
// B=4, T=1024 (32x32 grid), D=1024, NH=16, hd=64.
//
// R7 = R6 + one-line fix: MODE 4 V-transpose read-back row decompression
// ((srr0&31) + (srr0>>5)*64, matching the Q/K path; R6 dropped the >>5 term
// and scrambled half of V).
//
// R6 design: qkv GEMM writes Q,K in causal-POSITION order (row scatter) and
// V transposed [b][h][d][pos]. Attention hot loop: no permutation, all-b128
// staging (72-elem padded rows), 32 q-rows/wave, DPP softmax reductions.
//
// Batched ws (168 MB): [0,8)x_c->wout_c  [8,32)wq_c  [32,40)wo_c
//   [40,104) qk 4x16MB (pos-order [Q|K], ldc 2048) -> concat[40,72), wg[72,104)
//   [104,136) vt 4x8MB -> part  [136,168) y->gated
// ---------------------------------------------------------------------------

typedef __bf16 bf16_t;
typedef __bf16 bf16x4 __attribute__((ext_vector_type(4)));
typedef __bf16 bf16x8 __attribute__((ext_vector_type(8)));
typedef float  f32x4  __attribute__((ext_vector_type(4)));

#define MFMA16(a, b, c) __builtin_amdgcn_mfma_f32_16x16x32_bf16((a), (b), (c), 0, 0, 0)

__device__ __forceinline__ void async16(const bf16_t* g, bf16_t* l) {
  __builtin_amdgcn_global_load_lds((const __attribute__((address_space(1))) void*)g,
                                   (__attribute__((address_space(3))) void*)l,
                                   16, 0, 0);
}

// 16-lane (DPP row) all-reduce: xor1, xor2 quad-perms then row_ror:4, row_ror:8.
__device__ __forceinline__ float dpp_max16(float x) {
  float t;
  t = __builtin_bit_cast(float, __builtin_amdgcn_update_dpp(0, __builtin_bit_cast(int, x), 0xB1, 0xF, 0xF, true));
  x = fmaxf(x, t);
  t = __builtin_bit_cast(float, __builtin_amdgcn_update_dpp(0, __builtin_bit_cast(int, x), 0x4E, 0xF, 0xF, true));
  x = fmaxf(x, t);
  t = __builtin_bit_cast(float, __builtin_amdgcn_update_dpp(0, __builtin_bit_cast(int, x), 0x124, 0xF, 0xF, true));
  x = fmaxf(x, t);
  t = __builtin_bit_cast(float, __builtin_amdgcn_update_dpp(0, __builtin_bit_cast(int, x), 0x128, 0xF, 0xF, true));
  x = fmaxf(x, t);
  return x;
}
__device__ __forceinline__ float dpp_sum16(float x) {
  float t;
  t = __builtin_bit_cast(float, __builtin_amdgcn_update_dpp(0, __builtin_bit_cast(int, x), 0xB1, 0xF, 0xF, true));
  x += t;
  t = __builtin_bit_cast(float, __builtin_amdgcn_update_dpp(0, __builtin_bit_cast(int, x), 0x4E, 0xF, 0xF, true));
  x += t;
  t = __builtin_bit_cast(float, __builtin_amdgcn_update_dpp(0, __builtin_bit_cast(int, x), 0x124, 0xF, 0xF, true));
  x += t;
  t = __builtin_bit_cast(float, __builtin_amdgcn_update_dpp(0, __builtin_bit_cast(int, x), 0x128, 0xF, 0xF, true));
  x += t;
  return x;
}

struct Ptr4 { const bf16_t* p[4]; };

// Causal-order position p <-> token t (involution).
// dir0 lr: p; dir1 rl: 1023-p; dir2 td: transpose; dir3 bu: transpose(1023-p)
__device__ __forceinline__ int perm_t(int p, int dir) {
  int q = (dir & 1) ? (1023 - p) : p;
  if (dir >= 2) q = ((q & 31) << 5) | (q >> 5);
  return q;
}

// ------------------- batched fp32 -> bf16 convert (<=9 segments) ------------
struct CvtDesc {
  const float* src[9];
  bf16_t* dst[9];
  int n8[9];
};

__device__ __forceinline__ void cvt8(const float* in, bf16_t* out, int i) {
  const float4 a = ((const float4*)in)[i * 2];
  const float4 b = ((const float4*)in)[i * 2 + 1];
  bf16x8 o;
  o[0] = (bf16_t)a.x; o[1] = (bf16_t)a.y; o[2] = (bf16_t)a.z; o[3] = (bf16_t)a.w;
  o[4] = (bf16_t)b.x; o[5] = (bf16_t)b.y; o[6] = (bf16_t)b.z; o[7] = (bf16_t)b.w;
  ((bf16x8*)out)[i] = o;
}

__global__ __launch_bounds__(256) void cvt9_k(CvtDesc d) {
  const int seg = blockIdx.y;
  const int i = blockIdx.x * 256 + threadIdx.x;
  if (i >= d.n8[seg]) return;
  cvt8(d.src[seg], d.dst[seg], i);
}

// ---------------------------------------------------------------------------
// C = A * B^T, bf16 in, fp32 acc. 128x128 tile, BK=32, 4 waves 2x2 (m97).
// MODE 0: store bf16 C (at Cv + z*sCz)
// MODE 1: g = sigmoid(acc + bias[n]); store bf16 g * gin[m][n]
// MODE 3: split-K partial over k-range [z*koff, z*koff+K), fp32 C at Cv+z*sCz
// MODE 4: qkv special. dir = dirbase + z. Cols <2048 (Q,K): store rows at
//         causal position perm_t(t,dir), ldc=2048, into Cv+z*sCz. Cols >=2048
//         (V): store transposed to vtp+z*sVz as [b][h][d][pos].
// ---------------------------------------------------------------------------
template <int MODE>
__global__ __launch_bounds__(256) void gemm_bt(
    const bf16_t* __restrict__ A, long sAz, int lda,
    Ptr4 B4, int ldb,
    void* __restrict__ Cv, long sCz, int ldc, int K, int koff,
    const float* __restrict__ bias,
    const bf16_t* __restrict__ gin,
    bf16_t* __restrict__ vtp, long sVz, int dirbase) {
  constexpr int BM = 128, BN = 128, BK = 32;
  __shared__ __align__(16) bf16_t sA[BM * BK];
  __shared__ __align__(16) bf16_t sB[BN * BK];
  __shared__ __align__(16) float sC[64 * 144];  // also viewed as sCt[128][68]

  const int z = blockIdx.z;
  const bf16_t* Ap = A + (long)z * sAz;
  const bf16_t* Bp = B4.p[z];
  const int tid = threadIdx.x;
  const int wave = tid >> 6, lane = tid & 63;
  const int lane15 = lane & 15, quad = lane >> 4;
  const int bm = blockIdx.y * BM, bn = blockIdx.x * BN;
  const int wm = (wave >> 1) * 64, wn = (wave & 1) * 64;

  f32x4 acc[4][4];
#pragma unroll
  for (int i = 0; i < 4; i++)
#pragma unroll
    for (int j = 0; j < 4; j++) acc[i][j] = (f32x4){0.f, 0.f, 0.f, 0.f};

  const int srow = wave * 16 + (lane >> 2);
  const int skoff = (lane & 3) * 8;
  const int kz = (MODE == 3) ? z * koff : 0;
  const bf16_t* ga = Ap + (long)(bm + srow) * lda + skoff + kz;
  const bf16_t* gb = Bp + (long)(bn + srow) * ldb + skoff + kz;
  bf16_t* la = &sA[srow * BK + skoff];
  bf16_t* lb = &sB[srow * BK + skoff];

  for (int k0 = 0; k0 < K; k0 += BK) {
    __syncthreads();
    async16(ga + k0, la);
    async16(ga + k0 + (long)64 * lda, la + 64 * BK);
    async16(gb + k0, lb);
    async16(gb + k0 + (long)64 * ldb, lb + 64 * BK);
    __syncthreads();

    bf16x8 af[4], bfv[4];
#pragma unroll
    for (int i = 0; i < 4; i++)
      af[i] = *(const bf16x8*)&sA[(wm + i * 16 + lane15) * BK + quad * 8];
#pragma unroll
    for (int j = 0; j < 4; j++)
      bfv[j] = *(const bf16x8*)&sB[(wn + j * 16 + lane15) * BK + quad * 8];
#pragma unroll
    for (int i = 0; i < 4; i++)
#pragma unroll
      for (int j = 0; j < 4; j++)
        acc[i][j] = MFMA16(af[i], bfv[j], acc[i][j]);
  }

  // ------------- epilogue -------------
  if constexpr (MODE == 4) {
    const int dir = dirbase + z;
    if (bn < 2048) {  // Q,K: natural staging, row-permuted store, ldc=2048
      bf16_t* qkz = (bf16_t*)Cv + (long)z * sCz;
#pragma unroll
      for (int p = 0; p < 2; p++) {
        if (p) __syncthreads();
#pragma unroll
        for (int ii = 0; ii < 2; ii++) {
          const int i = 2 * p + ii;
          const int sr = (wm >> 1) + ii * 16 + quad * 4;
#pragma unroll
          for (int r = 0; r < 4; r++)
#pragma unroll
            for (int j = 0; j < 4; j++)
              sC[(sr + r) * 144 + wn + j * 16 + lane15] = acc[i][j][r];
        }
        __syncthreads();
#pragma unroll
        for (int c = 0; c < 8; c++) {
          const int idx = c * 256 + tid;
          const int srr = idx >> 5, chunk = idx & 31;
          const float4 v4 = *(const float4*)&sC[srr * 144 + chunk * 4];
          const int grow = bm + p * 32 + (srr & 31) + (srr >> 5) * 64;
          const int prow = (grow & ~1023) | perm_t(grow & 1023, dir);
          bf16x4 o;
          o[0] = (bf16_t)v4.x; o[1] = (bf16_t)v4.y;
          o[2] = (bf16_t)v4.z; o[3] = (bf16_t)v4.w;
          *(bf16x4*)(qkz + (long)prow * 2048 + bn + chunk * 4) = o;
        }
      }
    } else {  // V: transposed staging -> vt[b][h][d][pos]
      bf16_t* vz = vtp + (long)z * sVz;
      float* sCt = sC;  // [col 0..127][tok-compressed 0..63], stride 68
#pragma unroll
      for (int p = 0; p < 2; p++) {
        if (p) __syncthreads();
#pragma unroll
        for (int ii = 0; ii < 2; ii++) {
          const int i = 2 * p + ii;
          const int srb = (wm >> 1) + ii * 16 + quad * 4;
#pragma unroll
          for (int r = 0; r < 4; r++)
#pragma unroll
            for (int j = 0; j < 4; j++)
              sCt[(wn + j * 16 + lane15) * 68 + srb + r] = acc[i][j][r];
        }
        __syncthreads();
#pragma unroll
        for (int c = 0; c < 8; c++) {
          const int idx = c * 256 + tid;
          const int col = idx >> 4, tq = idx & 15;
          const int srr0 = (tq & 7) * 4 + (tq >> 3) * 32;
          const float4 v4 = *(const float4*)&sCt[col * 68 + srr0];
          // R7 FIX: decompress sCt row -> tile row (R6 dropped the >>5 term)
          const int t0 = (bm & 1023) + p * 32 + (srr0 & 31) + (srr0 >> 5) * 64;
          const int bb = bm >> 10;
          const int ch = bn + col - 2048;
          bf16_t* vrow = vz + (((long)bb * 16 + (ch >> 6)) * 64 + (ch & 63)) * 1024;
          if (dir == 0) {
            bf16x4 o;
            o[0] = (bf16_t)v4.x; o[1] = (bf16_t)v4.y;
            o[2] = (bf16_t)v4.z; o[3] = (bf16_t)v4.w;
            *(bf16x4*)(vrow + t0) = o;
          } else if (dir == 1) {
            bf16x4 o;
            o[0] = (bf16_t)v4.w; o[1] = (bf16_t)v4.z;
            o[2] = (bf16_t)v4.y; o[3] = (bf16_t)v4.x;
            *(bf16x4*)(vrow + (1020 - t0)) = o;
          } else {
            vrow[perm_t(t0 + 0, dir)] = (bf16_t)v4.x;
            vrow[perm_t(t0 + 1, dir)] = (bf16_t)v4.y;
            vrow[perm_t(t0 + 2, dir)] = (bf16_t)v4.z;
            vrow[perm_t(t0 + 3, dir)] = (bf16_t)v4.w;
          }
        }
      }
    }
  } else {
#pragma unroll
    for (int p = 0; p < 2; p++) {
      if (p) __syncthreads();
#pragma unroll
      for (int ii = 0; ii < 2; ii++) {
        const int i = 2 * p + ii;
        const int sr = (wm >> 1) + ii * 16 + quad * 4;
#pragma unroll
        for (int r = 0; r < 4; r++)
#pragma unroll
          for (int j = 0; j < 4; j++)
            sC[(sr + r) * 144 + wn + j * 16 + lane15] = acc[i][j][r];
      }
      __syncthreads();
#pragma unroll
      for (int c = 0; c < 8; c++) {
        const int idx = c * 256 + tid;
        const int srr = idx >> 5, chunk = idx & 31;
        const float4 v4 = *(const float4*)&sC[srr * 144 + chunk * 4];
        const int grow = bm + p * 32 + (srr & 31) + (srr >> 5) * 64;
        const int gcol = bn + chunk * 4;
        const long goff = (long)grow * ldc + gcol;
        if constexpr (MODE == 0) {
          bf16x4 o;
          o[0] = (bf16_t)v4.x; o[1] = (bf16_t)v4.y;
          o[2] = (bf16_t)v4.z; o[3] = (bf16_t)v4.w;
          *(bf16x4*)((bf16_t*)Cv + (long)z * sCz + goff) = o;
        } else if constexpr (MODE == 1) {
          const float4 bb = *(const float4*)&bias[gcol];
          const bf16x4 gv = *(const bf16x4*)&gin[goff];
          bf16x4 o;
          o[0] = (bf16_t)((float)gv[0] / (1.f + __expf(-(v4.x + bb.x))));
          o[1] = (bf16_t)((float)gv[1] / (1.f + __expf(-(v4.y + bb.y))));
          o[2] = (bf16_t)((float)gv[2] / (1.f + __expf(-(v4.z + bb.z))));
          o[3] = (bf16_t)((float)gv[3] / (1.f + __expf(-(v4.w + bb.w))));
          *(bf16x4*)((bf16_t*)Cv + goff) = o;
        } else {
          *(float4*)((float*)Cv + (long)z * sCz + goff) = v4;
        }
      }
    }
  }
}

// ---------------------------------------------------------------------------
// Flash attention, pure-causal in position space (no perm in hot loop).
// Block = 4 waves x 32 q-rows = 128 q-rows; grid (8, 256): y = zi*64 + b*16+h.
// 64-key tiles, ktiles = 2*qt+2. K from qk (pos rows), V^T from vt [d][pos].
// All LDS rows padded to 72 elems (b128 at bank floor). DPP softmax reduce.
// ---------------------------------------------------------------------------
__global__ __launch_bounds__(256, 3) void attn_k(
    const bf16_t* __restrict__ qk, long sQz,
    const bf16_t* __restrict__ vt, long sVz,
    bf16_t* __restrict__ y, long sYz, int dir0) {
  const int zi = blockIdx.y >> 6;
  const int bh = blockIdx.y & 63;
  const int dir = dir0 + zi;
  const int b = bh >> 4, h = bh & 15;
  const int qt = (int)(gridDim.x - 1 - blockIdx.x);  // heavy blocks first
  const int tid = threadIdx.x;
  const int wave = tid >> 6, lane = tid & 63;
  const int lane15 = lane & 15, quad = lane >> 4;
  const int hoff = h * 64;
  const bf16_t* base = qk + (long)zi * sQz + (long)b * 1024 * 2048;
  const bf16_t* vth = vt + (long)zi * sVz + ((long)b * 16 + h) * 64 * 1024;
  bf16_t* yd = y + (long)zi * sYz;

  __shared__ __align__(16) bf16_t sK[64 * 72];
  __shared__ __align__(16) bf16_t sVt[64 * 72];
  __shared__ __align__(16) bf16_t sP[4][32 * 72];

  // Q fragments: 2 row-groups of 16, A-layout (m=lane15, k=quad*8+j)
  bf16x8 qa[2][2];
#pragma unroll
  for (int g = 0; g < 2; g++) {
    const int row = qt * 128 + wave * 32 + g * 16 + lane15;
    qa[g][0] = *(const bf16x8*)(base + (long)row * 2048 + hoff + quad * 8);
    qa[g][1] = *(const bf16x8*)(base + (long)row * 2048 + hoff + 32 + quad * 8);
  }

  const float FNEG = -1e30f;
  float mrow[2][4], lrow[2][4];
  f32x4 o[2][4];
#pragma unroll
  for (int g = 0; g < 2; g++)
#pragma unroll
    for (int r = 0; r < 4; r++) { mrow[g][r] = FNEG; lrow[g][r] = 0.f; }
#pragma unroll
  for (int g = 0; g < 2; g++)
#pragma unroll
    for (int d4 = 0; d4 < 4; d4++) o[g][d4] = (f32x4){0.f, 0.f, 0.f, 0.f};

  const int krow = tid >> 3, kd = (tid & 7) * 8;   // K: 32 rows x 128B per pass
  const int vd = tid >> 2, pc = (tid & 3) * 8;     // V: 64 d-rows x 64B per pass
  const bf16_t* kb_g = base + 1024 + hoff;

  // preload tile 0
  bf16x8 kA = *(const bf16x8*)(kb_g + (long)krow * 2048 + kd);
  bf16x8 kB = *(const bf16x8*)(kb_g + (long)(32 + krow) * 2048 + kd);
  bf16x8 vA = *(const bf16x8*)(vth + (long)vd * 1024 + pc);
  bf16x8 vB = *(const bf16x8*)(vth + (long)vd * 1024 + 32 + pc);

  const int ktiles = 2 * qt + 2;
  for (int kt = 0; kt < ktiles; kt++) {
    __syncthreads();  // prev tile's LDS reads done
    *(bf16x8*)&sK[krow * 72 + kd] = kA;
    *(bf16x8*)&sK[(krow + 32) * 72 + kd] = kB;
    *(bf16x8*)&sVt[vd * 72 + pc] = vA;
    *(bf16x8*)&sVt[vd * 72 + 32 + pc] = vB;
    __syncthreads();  // staging visible
    if (kt + 1 < ktiles) {  // prefetch next tile into regs (overlaps compute)
      const int nb = (kt + 1) * 64;
      kA = *(const bf16x8*)(kb_g + (long)(nb + krow) * 2048 + kd);
      kB = *(const bf16x8*)(kb_g + (long)(nb + 32 + krow) * 2048 + kd);
      vA = *(const bf16x8*)(vth + (long)vd * 1024 + nb + pc);
      vB = *(const bf16x8*)(vth + (long)vd * 1024 + nb + 32 + pc);
    }
    const int kbase = kt * 64;

    // S = Q K^T: per g, 4 key-groups x 2 k-chunks
    bf16x8 kb[4][2];
#pragma unroll
    for (int ns = 0; ns < 4; ns++) {
      kb[ns][0] = *(const bf16x8*)&sK[(ns * 16 + lane15) * 72 + quad * 8];
      kb[ns][1] = *(const bf16x8*)&sK[(ns * 16 + lane15) * 72 + 32 + quad * 8];
    }
    f32x4 s[2][4];
#pragma unroll
    for (int g = 0; g < 2; g++)
#pragma unroll
      for (int ns = 0; ns < 4; ns++) {
        f32x4 t = (f32x4){0.f, 0.f, 0.f, 0.f};
        t = MFMA16(qa[g][0], kb[ns][0], t);
        t = MFMA16(qa[g][1], kb[ns][1], t);
        s[g][ns] = t;
      }
    // scale + causal mask
#pragma unroll
    for (int g = 0; g < 2; g++) {
      const int qc = qt * 128 + wave * 32 + g * 16 + quad * 4;
#pragma unroll
      for (int ns = 0; ns < 4; ns++) {
        const int kp = kbase + ns * 16 + lane15;
#pragma unroll
        for (int r = 0; r < 4; r++) {
          const float v = s[g][ns][r] * 0.125f;
          s[g][ns][r] = (kp <= qc + r) ? v : FNEG;
        }
      }
    }
    // online softmax (DPP 16-lane reductions)
#pragma unroll
    for (int g = 0; g < 2; g++) {
      float alpha[4];
#pragma unroll
      for (int r = 0; r < 4; r++) {
        float tm = fmaxf(fmaxf(s[g][0][r], s[g][1][r]),
                         fmaxf(s[g][2][r], s[g][3][r]));
        tm = dpp_max16(tm);
        const float mn = fmaxf(mrow[g][r], tm);
        alpha[r] = __expf(mrow[g][r] - mn);
        mrow[g][r] = mn;
      }
#pragma unroll
      for (int ns = 0; ns < 4; ns++)
#pragma unroll
        for (int r = 0; r < 4; r++)
          s[g][ns][r] = __expf(s[g][ns][r] - mrow[g][r]);
#pragma unroll
      for (int r = 0; r < 4; r++) {
        float ts = (s[g][0][r] + s[g][1][r]) + (s[g][2][r] + s[g][3][r]);
        ts = dpp_sum16(ts);
        lrow[g][r] = lrow[g][r] * alpha[r] + ts;
      }
#pragma unroll
      for (int d4 = 0; d4 < 4; d4++)
#pragma unroll
        for (int r = 0; r < 4; r++) o[g][d4][r] *= alpha[r];
      // P: C-layout -> bf16 A-layout via per-wave LDS scratch
#pragma unroll
      for (int ns = 0; ns < 4; ns++)
#pragma unroll
        for (int r = 0; r < 4; r++)
          sP[wave][(g * 16 + quad * 4 + r) * 72 + ns * 16 + lane15] =
              (bf16_t)s[g][ns][r];
    }
    // PV
    bf16x8 vb[4][2];
#pragma unroll
    for (int d4 = 0; d4 < 4; d4++) {
      vb[d4][0] = *(const bf16x8*)&sVt[(d4 * 16 + lane15) * 72 + quad * 8];
      vb[d4][1] = *(const bf16x8*)&sVt[(d4 * 16 + lane15) * 72 + 32 + quad * 8];
    }
#pragma unroll
    for (int g = 0; g < 2; g++) {
      const bf16x8 pa0 = *(const bf16x8*)&sP[wave][(g * 16 + lane15) * 72 + quad * 8];
      const bf16x8 pa1 = *(const bf16x8*)&sP[wave][(g * 16 + lane15) * 72 + 32 + quad * 8];
#pragma unroll
      for (int d4 = 0; d4 < 4; d4++) {
        o[g][d4] = MFMA16(pa0, vb[d4][0], o[g][d4]);
        o[g][d4] = MFMA16(pa1, vb[d4][1], o[g][d4]);
      }
    }
  }

  // epilogue: normalize, bounce through sP (per-wave), vector store, token scatter
#pragma unroll
  for (int g = 0; g < 2; g++)
#pragma unroll
    for (int r = 0; r < 4; r++) {
      const float rinv = 1.f / fmaxf(lrow[g][r], 1e-20f);
#pragma unroll
      for (int d4 = 0; d4 < 4; d4++)
        sP[wave][(g * 16 + quad * 4 + r) * 72 + d4 * 16 + lane15] =
            (bf16_t)(o[g][d4][r] * rinv);
    }
#pragma unroll
  for (int g = 0; g < 2; g++) {
    const bf16x8 o0 = *(const bf16x8*)&sP[wave][(g * 16 + lane15) * 72 + quad * 16];
    const bf16x8 o1 = *(const bf16x8*)&sP[wave][(g * 16 + lane15) * 72 + quad * 16 + 8];
    const int tok = perm_t(qt * 128 + wave * 32 + g * 16 + lane15, dir);
    bf16_t* yr = yd + ((long)b * 1024 + tok) * 1024 + hoff + quad * 16;
    *(bf16x8*)yr = o0;
    *(bf16x8*)(yr + 8) = o1;
  }
}

// ---------------------------------------------------------------------------
// RMSNorm over rows of 1024: v = P0 + P1 + x (split-K reduce + residual).
// ---------------------------------------------------------------------------
__global__ __launch_bounds__(256) void rmsnorm_k(const float* __restrict__ p0,
                                                 const float* __restrict__ p1,
                                                 const float* __restrict__ x,
                                                 const float* __restrict__ w,
                                                 float* __restrict__ out) {
  const int row = blockIdx.x, tid = threadIdx.x;
  const long off = (long)row * 1024;
  const float4 a = ((const float4*)(p0 + off))[tid];
  const float4 bq = ((const float4*)(p1 + off))[tid];
  const float4 c = ((const float4*)(x + off))[tid];
  float4 v;
  v.x = a.x + bq.x + c.x;
  v.y = a.y + bq.y + c.y;
  v.z = a.z + bq.z + c.z;
  v.w = a.w + bq.w + c.w;
  float ss = v.x * v.x + v.y * v.y + v.z * v.z + v.w * v.w;
#pragma unroll
  for (int o2 = 32; o2 >= 1; o2 >>= 1) ss += __shfl_xor(ss, o2);
  __shared__ float wsum[4];
  if ((tid & 63) == 0) wsum[tid >> 6] = ss;
  __syncthreads();
  const float tot = wsum[0] + wsum[1] + wsum[2] + wsum[3];
  const float norm = rsqrtf(tot * (1.f / 1024.f) + 1e-6f);
  const float4 wv = ((const float4*)w)[tid];
  v.x = v.x * norm * wv.x;
  v.y = v.y * norm * wv.y;
  v.z = v.z * norm * wv.z;
  v.w = v.w * norm * wv.w;
  ((float4*)(out + off))[tid] = v;
}

// ---------------------------------------------------------------------------
extern "C" void kernel_launch(void* const* d_in, const int* in_sizes, int n_in,
                              void* d_out, int out_size, void* d_ws, size_t ws_size,
                              hipStream_t stream) {
  (void)in_sizes; (void)n_in; (void)out_size;
  const float* xf = (const float*)d_in[0];
  const float* wqkv_f[4] = {(const float*)d_in[1], (const float*)d_in[3],
                            (const float*)d_in[5], (const float*)d_in[7]};
  const float* wo_f[4] = {(const float*)d_in[2], (const float*)d_in[4],
                          (const float*)d_in[6], (const float*)d_in[8]};
  const float* wgate_f = (const float*)d_in[9];
  const float* bgate_f = (const float*)d_in[10];
  const float* wout_f = (const float*)d_in[11];
  const float* normw_f = (const float*)d_in[12];

  const long MB = 1l << 20;
  char* ws = (char*)d_ws;
  const dim3 blk(256);
  const bool batched = ws_size >= (size_t)(168 * MB);
  const long sQK = 4096l * 2048;   // qk per-dir elems (16 MB)
  const long sVT = 4096l * 1024;   // vt per-dir elems (8 MB)
  const long sY  = 4096l * 1024;   // y per-dir elems (8 MB)

  if (batched) {
    bf16_t* x_c    = (bf16_t*)(ws);              // 8 MB   -> wout_c later
    bf16_t* wq_c   = (bf16_t*)(ws + 8 * MB);     // 24 MB
    bf16_t* wo_c   = (bf16_t*)(ws + 32 * MB);    // 8 MB
    bf16_t* qk     = (bf16_t*)(ws + 40 * MB);    // 64 MB (4 dirs, pos order)
    bf16_t* vt     = (bf16_t*)(ws + 104 * MB);   // 32 MB (4 dirs, [b][h][d][p])
    bf16_t* y      = (bf16_t*)(ws + 136 * MB);   // 32 MB -> gated
    bf16_t* concat = (bf16_t*)(ws + 40 * MB);    // 32 MB (phase 2, qk dirs 0-1 dead)
    bf16_t* wg_c   = (bf16_t*)(ws + 72 * MB);    // 32 MB (qk dirs 2-3 dead)
    bf16_t* wout_c = (bf16_t*)(ws);              // 8 MB (x dead)
    float*  part   = (float*)(ws + 104 * MB);    // 32 MB (vt dead)
    bf16_t* gated  = y;

    {  // convert x, wqkv x4, wo x4
      CvtDesc cd;
      cd.src[0] = xf; cd.dst[0] = x_c; cd.n8[0] = 4194304 / 8;
      for (int d = 0; d < 4; d++) {
        cd.src[1 + d] = wqkv_f[d];
        cd.dst[1 + d] = wq_c + (long)d * 3145728;
        cd.n8[1 + d] = 3145728 / 8;
        cd.src[5 + d] = wo_f[d];
        cd.dst[5 + d] = wo_c + (long)d * 1048576;
        cd.n8[5 + d] = 1048576 / 8;
      }
      cvt9_k<<<dim3(2048, 9), blk, 0, stream>>>(cd);
    }
    {  // qkv GEMM, 4 dirs: Q,K -> pos order; V -> vt transposed
      Ptr4 bq{{wq_c, wq_c + 3145728, wq_c + 2l * 3145728, wq_c + 3l * 3145728}};
      gemm_bt<4><<<dim3(24, 32, 4), blk, 0, stream>>>(
          x_c, 0, 1024, bq, 1024, qk, sQK, 2048, 1024, 0, nullptr, nullptr,
          vt, sVT, 0);
    }
    attn_k<<<dim3(8, 256), blk, 0, stream>>>(qk, sQK, vt, sVT, y, sY, 0);
    {  // convert wgate + wout (after attn: overlays qk/x space)
      CvtDesc cd;
      for (int s = 0; s < 9; s++) cd.n8[s] = 0;
      cd.src[0] = wgate_f; cd.dst[0] = wg_c; cd.n8[0] = 16777216 / 8;
      cd.src[1] = wout_f; cd.dst[1] = wout_c; cd.n8[1] = 4194304 / 8;
      cvt9_k<<<dim3(8192, 2), blk, 0, stream>>>(cd);
    }
    {  // out-proj, z-batched -> concat[:, z*1024:(z+1)*1024]
      Ptr4 b4{{wo_c, wo_c + 1048576, wo_c + 2097152, wo_c + 3145728}};
      gemm_bt<0><<<dim3(8, 32, 4), blk, 0, stream>>>(
          y, sY, 1024, b4, 1024, concat, 1024, 4096, 1024, 0, nullptr, nullptr,
          nullptr, 0, 0);
    }
    {  // gated = sigmoid(concat@wg^T + b) * concat
      Ptr4 b4{{wg_c, wg_c, wg_c, wg_c}};
      gemm_bt<1><<<dim3(32, 32, 1), blk, 0, stream>>>(
          concat, 0, 4096, b4, 4096, gated, 0, 4096, 4096, 0, bgate_f, concat,
          nullptr, 0, 0);
    }
    {  // split-K=2 w_out partials
      Ptr4 b4{{wout_c, wout_c, wout_c, wout_c}};
      gemm_bt<3><<<dim3(8, 32, 2), blk, 0, stream>>>(
          gated, 0, 4096, b4, 4096, part, (long)4096 * 1024, 1024, 2048, 2048,
          nullptr, nullptr, nullptr, 0, 0);
    }
    rmsnorm_k<<<dim3(4096), blk, 0, stream>>>(part, part + (long)4096 * 1024,
                                              xf, normw_f, (float*)d_out);
  } else {
    // fallback (96 MB): per-dir qkv+attn
    bf16_t* x_c    = (bf16_t*)(ws);              // 8 MB
    bf16_t* wq_c   = (bf16_t*)(ws + 8 * MB);     // 24 MB
    bf16_t* qk_d   = (bf16_t*)(ws + 32 * MB);    // 16 MB (per-dir)
    bf16_t* vt_d   = (bf16_t*)(ws + 48 * MB);    // 8 MB (per-dir)
    bf16_t* wo_c   = (bf16_t*)(ws + 56 * MB);    // 8 MB
    bf16_t* y      = (bf16_t*)(ws + 64 * MB);    // 32 MB -> gated
    bf16_t* concat = (bf16_t*)(ws);              // 32 MB (phase 2)
    bf16_t* wg_c   = (bf16_t*)(ws + 32 * MB);    // 32 MB (after out-proj)
    bf16_t* wout_c = (bf16_t*)(ws);              // 8 MB (after gate)
    float*  part   = (float*)(ws + 8 * MB);      // 32 MB
    bf16_t* gated  = y;

    {
      CvtDesc cd;
      cd.src[0] = xf; cd.dst[0] = x_c; cd.n8[0] = 4194304 / 8;
      for (int d = 0; d < 4; d++) {
        cd.src[1 + d] = wqkv_f[d];
        cd.dst[1 + d] = wq_c + (long)d * 3145728;
        cd.n8[1 + d] = 3145728 / 8;
        cd.src[5 + d] = wo_f[d];
        cd.dst[5 + d] = wo_c + (long)d * 1048576;
        cd.n8[5 + d] = 1048576 / 8;
      }
      cvt9_k<<<dim3(2048, 9), blk, 0, stream>>>(cd);
    }
    for (int d = 0; d < 4; d++) {
      const bf16_t* wq_d = wq_c + (long)d * 3145728;
      Ptr4 bq{{wq_d, wq_d, wq_d, wq_d}};
      gemm_bt<4><<<dim3(24, 32, 1), blk, 0, stream>>>(
          x_c, 0, 1024, bq, 1024, qk_d, 0, 2048, 1024, 0, nullptr, nullptr,
          vt_d, 0, d);
      attn_k<<<dim3(8, 64), blk, 0, stream>>>(qk_d, 0, vt_d, 0,
                                              y + (long)d * sY, 0, d);
    }
    {
      Ptr4 b4{{wo_c, wo_c + 1048576, wo_c + 2097152, wo_c + 3145728}};
      gemm_bt<0><<<dim3(8, 32, 4), blk, 0, stream>>>(
          y, sY, 1024, b4, 1024, concat, 1024, 4096, 1024, 0, nullptr, nullptr,
          nullptr, 0, 0);
    }
    {
      CvtDesc cd;
      for (int s = 0; s < 9; s++) cd.n8[s] = 0;
      cd.src[0] = wgate_f; cd.dst[0] = wg_c; cd.n8[0] = 16777216 / 8;
      cvt9_k<<<dim3(8192, 1), blk, 0, stream>>>(cd);
    }
    {
      Ptr4 b4{{wg_c, wg_c, wg_c, wg_c}};
      gemm_bt<1><<<dim3(32, 32, 1), blk, 0, stream>>>(
          concat, 0, 4096, b4, 4096, gated, 0, 4096, 4096, 0, bgate_f, concat,
          nullptr, 0, 0);
    }
    {
      CvtDesc cd;
      for (int s = 0; s < 9; s++) cd.n8[s] = 0;
      cd.src[0] = wout_f; cd.dst[0] = wout_c; cd.n8[0] = 4194304 / 8;
      cvt9_k<<<dim3(2048, 1), blk, 0, stream>>>(cd);
    }
    {
      Ptr4 b4{{wout_c, wout_c, wout_c, wout_c}};
      gemm_bt<3><<<dim3(8, 32, 2), blk, 0, stream>>>(
          gated, 0, 4096, b4, 4096, part, (long)4096 * 1024, 1024, 2048, 2048,
          nullptr, nullptr, nullptr, 0, 0);
    }
    rmsnorm_k<<<dim3(4096), blk, 0, stream>>>(part, part + (long)4096 * 1024,
                                              xf, normw_f, (float*)d_out);
  }
}

// Round 8
// 848.683 us; speedup vs baseline: 1.2939x; 1.0119x over previous
//
#include <hip/hip_runtime.h>
#include <hip/hip_bf16.h>
#include <math.h>

// ---------------------------------------------------------------------------
// MultiDirectionalGridAttention. FP32 in/out; bf16 MFMA core, fp32 accum.
// B=4, T=1024 (32x32 grid), D=1024, NH=16, hd=64.
//
// R8 = R7 + GEMM epilogue LDS overlay: the fp32 epilogue staging buffer now
// reuses the (dead) sA/sB staging memory and is 32x144 f32 (18.4 KB total LDS
// vs R7's 53 KB) -> occupancy limited by VGPR (~7 blocks/CU) instead of LDS
// (~2 blocks/CU). 4 epilogue passes (one acc[i] each); MODE 4 V-transpose is
// 4 passes of 64 cols x 68 (17.4 KB).
//
// R6/R7 design: qkv GEMM writes Q,K in causal-POSITION order (row scatter)
// and V transposed [b][h][d][pos]. Attention hot loop: no permutation,
// all-b128 staging (72-elem padded rows), 32 q-rows/wave, DPP softmax.
//
// Batched ws (168 MB): [0,8)x_c->wout_c  [8,32)wq_c  [32,40)wo_c
//   [40,104) qk 4x16MB (pos-order [Q|K], ldc 2048) -> concat[40,72), wg[72,104)
//   [104,136) vt 4x8MB -> part  [136,168) y->gated
// ---------------------------------------------------------------------------

typedef __bf16 bf16_t;
typedef __bf16 bf16x4 __attribute__((ext_vector_type(4)));
typedef __bf16 bf16x8 __attribute__((ext_vector_type(8)));
typedef float  f32x4  __attribute__((ext_vector_type(4)));

#define MFMA16(a, b, c) __builtin_amdgcn_mfma_f32_16x16x32_bf16((a), (b), (c), 0, 0, 0)

__device__ __forceinline__ void async16(const bf16_t* g, bf16_t* l) {
  __builtin_amdgcn_global_load_lds((const __attribute__((address_space(1))) void*)g,
                                   (__attribute__((address_space(3))) void*)l,
                                   16, 0, 0);
}

// 16-lane (DPP row) all-reduce: xor1, xor2 quad-perms then row_ror:4, row_ror:8.
__device__ __forceinline__ float dpp_max16(float x) {
  float t;
  t = __builtin_bit_cast(float, __builtin_amdgcn_update_dpp(0, __builtin_bit_cast(int, x), 0xB1, 0xF, 0xF, true));
  x = fmaxf(x, t);
  t = __builtin_bit_cast(float, __builtin_amdgcn_update_dpp(0, __builtin_bit_cast(int, x), 0x4E, 0xF, 0xF, true));
  x = fmaxf(x, t);
  t = __builtin_bit_cast(float, __builtin_amdgcn_update_dpp(0, __builtin_bit_cast(int, x), 0x124, 0xF, 0xF, true));
  x = fmaxf(x, t);
  t = __builtin_bit_cast(float, __builtin_amdgcn_update_dpp(0, __builtin_bit_cast(int, x), 0x128, 0xF, 0xF, true));
  x = fmaxf(x, t);
  return x;
}
__device__ __forceinline__ float dpp_sum16(float x) {
  float t;
  t = __builtin_bit_cast(float, __builtin_amdgcn_update_dpp(0, __builtin_bit_cast(int, x), 0xB1, 0xF, 0xF, true));
  x += t;
  t = __builtin_bit_cast(float, __builtin_amdgcn_update_dpp(0, __builtin_bit_cast(int, x), 0x4E, 0xF, 0xF, true));
  x += t;
  t = __builtin_bit_cast(float, __builtin_amdgcn_update_dpp(0, __builtin_bit_cast(int, x), 0x124, 0xF, 0xF, true));
  x += t;
  t = __builtin_bit_cast(float, __builtin_amdgcn_update_dpp(0, __builtin_bit_cast(int, x), 0x128, 0xF, 0xF, true));
  x += t;
  return x;
}

struct Ptr4 { const bf16_t* p[4]; };

// Causal-order position p <-> token t (involution).
// dir0 lr: p; dir1 rl: 1023-p; dir2 td: transpose; dir3 bu: transpose(1023-p)
__device__ __forceinline__ int perm_t(int p, int dir) {
  int q = (dir & 1) ? (1023 - p) : p;
  if (dir >= 2) q = ((q & 31) << 5) | (q >> 5);
  return q;
}

// ------------------- batched fp32 -> bf16 convert (<=9 segments) ------------
struct CvtDesc {
  const float* src[9];
  bf16_t* dst[9];
  int n8[9];
};

__device__ __forceinline__ void cvt8(const float* in, bf16_t* out, int i) {
  const float4 a = ((const float4*)in)[i * 2];
  const float4 b = ((const float4*)in)[i * 2 + 1];
  bf16x8 o;
  o[0] = (bf16_t)a.x; o[1] = (bf16_t)a.y; o[2] = (bf16_t)a.z; o[3] = (bf16_t)a.w;
  o[4] = (bf16_t)b.x; o[5] = (bf16_t)b.y; o[6] = (bf16_t)b.z; o[7] = (bf16_t)b.w;
  ((bf16x8*)out)[i] = o;
}

__global__ __launch_bounds__(256) void cvt9_k(CvtDesc d) {
  const int seg = blockIdx.y;
  const int i = blockIdx.x * 256 + threadIdx.x;
  if (i >= d.n8[seg]) return;
  cvt8(d.src[seg], d.dst[seg], i);
}

// ---------------------------------------------------------------------------
// C = A * B^T, bf16 in, fp32 acc. 128x128 tile, BK=32, 4 waves 2x2 (m97).
// Epilogue staging OVERLAYS sA/sB (dead after K-loop): 18.4 KB total LDS.
// MODE 0: store bf16 C (at Cv + z*sCz)
// MODE 1: g = sigmoid(acc + bias[n]); store bf16 g * gin[m][n]
// MODE 3: split-K partial over k-range [z*koff, z*koff+K), fp32 C at Cv+z*sCz
// MODE 4: qkv special. dir = dirbase + z. Cols <2048 (Q,K): rows stored at
//         causal position perm_t(t,dir), ldc=2048. Cols >=2048 (V): stored
//         transposed to vtp+z*sVz as [b][h][d][pos].
// ---------------------------------------------------------------------------
template <int MODE>
__global__ __launch_bounds__(256) void gemm_bt(
    const bf16_t* __restrict__ A, long sAz, int lda,
    Ptr4 B4, int ldb,
    void* __restrict__ Cv, long sCz, int ldc, int K, int koff,
    const float* __restrict__ bias,
    const bf16_t* __restrict__ gin,
    bf16_t* __restrict__ vtp, long sVz, int dirbase) {
  constexpr int BM = 128, BN = 128, BK = 32;
  // 18432 B shared: [K-loop] sA(8K)+sB(8K) | [epilogue] sC 32x144 f32 /
  // sCt 64x68 f32 (overlay -- sA/sB dead once the K-loop exits)
  __shared__ __align__(16) char smem[18432];
  bf16_t* sA = (bf16_t*)smem;
  bf16_t* sB = (bf16_t*)(smem + BM * BK * 2);
  float* sC = (float*)smem;

  const int z = blockIdx.z;
  const bf16_t* Ap = A + (long)z * sAz;
  const bf16_t* Bp = B4.p[z];
  const int tid = threadIdx.x;
  const int wave = tid >> 6, lane = tid & 63;
  const int lane15 = lane & 15, quad = lane >> 4;
  const int bm = blockIdx.y * BM, bn = blockIdx.x * BN;
  const int wm = (wave >> 1) * 64, wn = (wave & 1) * 64;

  f32x4 acc[4][4];
#pragma unroll
  for (int i = 0; i < 4; i++)
#pragma unroll
    for (int j = 0; j < 4; j++) acc[i][j] = (f32x4){0.f, 0.f, 0.f, 0.f};

  const int srow = wave * 16 + (lane >> 2);
  const int skoff = (lane & 3) * 8;
  const int kz = (MODE == 3) ? z * koff : 0;
  const bf16_t* ga = Ap + (long)(bm + srow) * lda + skoff + kz;
  const bf16_t* gb = Bp + (long)(bn + srow) * ldb + skoff + kz;
  bf16_t* la = &sA[srow * BK + skoff];
  bf16_t* lb = &sB[srow * BK + skoff];

  for (int k0 = 0; k0 < K; k0 += BK) {
    __syncthreads();
    async16(ga + k0, la);
    async16(ga + k0 + (long)64 * lda, la + 64 * BK);
    async16(gb + k0, lb);
    async16(gb + k0 + (long)64 * ldb, lb + 64 * BK);
    __syncthreads();

    bf16x8 af[4], bfv[4];
#pragma unroll
    for (int i = 0; i < 4; i++)
      af[i] = *(const bf16x8*)&sA[(wm + i * 16 + lane15) * BK + quad * 8];
#pragma unroll
    for (int j = 0; j < 4; j++)
      bfv[j] = *(const bf16x8*)&sB[(wn + j * 16 + lane15) * BK + quad * 8];
#pragma unroll
    for (int i = 0; i < 4; i++)
#pragma unroll
      for (int j = 0; j < 4; j++)
        acc[i][j] = MFMA16(af[i], bfv[j], acc[i][j]);
  }

  __syncthreads();  // all waves done reading sA/sB before the sC overlay

  // ------------- epilogue -------------
  if constexpr (MODE == 4) {
    const int dir = dirbase + z;
    if (bn < 2048) {  // Q,K: 4 passes of 16+16 rows, row-permuted store
      bf16_t* qkz = (bf16_t*)Cv + (long)z * sCz;
#pragma unroll
      for (int p = 0; p < 4; p++) {
        if (p) __syncthreads();
        const int sr = (wm >> 2) + quad * 4;  // wm=0 -> 0..15, wm=64 -> 16..31
#pragma unroll
        for (int r = 0; r < 4; r++)
#pragma unroll
          for (int j = 0; j < 4; j++)
            sC[(sr + r) * 144 + wn + j * 16 + lane15] = acc[p][j][r];
        __syncthreads();
#pragma unroll
        for (int c = 0; c < 4; c++) {
          const int idx = c * 256 + tid;
          const int srr = idx >> 5, chunk = idx & 31;
          const float4 v4 = *(const float4*)&sC[srr * 144 + chunk * 4];
          const int grow = bm + p * 16 + (srr & 15) + (srr >> 4) * 64;
          const int prow = (grow & ~1023) | perm_t(grow & 1023, dir);
          bf16x4 o;
          o[0] = (bf16_t)v4.x; o[1] = (bf16_t)v4.y;
          o[2] = (bf16_t)v4.z; o[3] = (bf16_t)v4.w;
          *(bf16x4*)(qkz + (long)prow * 2048 + bn + chunk * 4) = o;
        }
      }
    } else {  // V: 4 passes (row-half p x col-half q) -> vt[b][h][d][pos]
      bf16_t* vz = vtp + (long)z * sVz;
      float* sCt = sC;  // [col 0..63][tok-compressed 0..63], stride 68
#pragma unroll
      for (int p = 0; p < 2; p++)
#pragma unroll
        for (int q = 0; q < 2; q++) {
          if (p || q) __syncthreads();
          if ((wave & 1) == q) {  // only waves with wn == 64q hold these cols
#pragma unroll
            for (int ii = 0; ii < 2; ii++) {
              const int i = 2 * p + ii;
              const int srb = (wm >> 1) + ii * 16 + quad * 4;
#pragma unroll
              for (int r = 0; r < 4; r++)
#pragma unroll
                for (int j = 0; j < 4; j++)
                  sCt[(j * 16 + lane15) * 68 + srb + r] = acc[i][j][r];
            }
          }
          __syncthreads();
#pragma unroll
          for (int c = 0; c < 4; c++) {
            const int idx = c * 256 + tid;
            const int col = idx >> 4, tq = idx & 15;
            const int srr0 = (tq & 7) * 4 + (tq >> 3) * 32;
            const float4 v4 = *(const float4*)&sCt[col * 68 + srr0];
            const int t0 = (bm & 1023) + p * 32 + (srr0 & 31) + (srr0 >> 5) * 64;
            const int bb = bm >> 10;
            const int ch = bn + 64 * q + col - 2048;
            bf16_t* vrow =
                vz + (((long)bb * 16 + (ch >> 6)) * 64 + (ch & 63)) * 1024;
            if (dir == 0) {
              bf16x4 o;
              o[0] = (bf16_t)v4.x; o[1] = (bf16_t)v4.y;
              o[2] = (bf16_t)v4.z; o[3] = (bf16_t)v4.w;
              *(bf16x4*)(vrow + t0) = o;
            } else if (dir == 1) {
              bf16x4 o;
              o[0] = (bf16_t)v4.w; o[1] = (bf16_t)v4.z;
              o[2] = (bf16_t)v4.y; o[3] = (bf16_t)v4.x;
              *(bf16x4*)(vrow + (1020 - t0)) = o;
            } else {
              vrow[perm_t(t0 + 0, dir)] = (bf16_t)v4.x;
              vrow[perm_t(t0 + 1, dir)] = (bf16_t)v4.y;
              vrow[perm_t(t0 + 2, dir)] = (bf16_t)v4.z;
              vrow[perm_t(t0 + 3, dir)] = (bf16_t)v4.w;
            }
          }
        }
    }
  } else {
#pragma unroll
    for (int p = 0; p < 4; p++) {
      if (p) __syncthreads();
      const int sr = (wm >> 2) + quad * 4;
#pragma unroll
      for (int r = 0; r < 4; r++)
#pragma unroll
        for (int j = 0; j < 4; j++)
          sC[(sr + r) * 144 + wn + j * 16 + lane15] = acc[p][j][r];
      __syncthreads();
#pragma unroll
      for (int c = 0; c < 4; c++) {
        const int idx = c * 256 + tid;
        const int srr = idx >> 5, chunk = idx & 31;
        const float4 v4 = *(const float4*)&sC[srr * 144 + chunk * 4];
        const int grow = bm + p * 16 + (srr & 15) + (srr >> 4) * 64;
        const int gcol = bn + chunk * 4;
        const long goff = (long)grow * ldc + gcol;
        if constexpr (MODE == 0) {
          bf16x4 o;
          o[0] = (bf16_t)v4.x; o[1] = (bf16_t)v4.y;
          o[2] = (bf16_t)v4.z; o[3] = (bf16_t)v4.w;
          *(bf16x4*)((bf16_t*)Cv + (long)z * sCz + goff) = o;
        } else if constexpr (MODE == 1) {
          const float4 bb = *(const float4*)&bias[gcol];
          const bf16x4 gv = *(const bf16x4*)&gin[goff];
          bf16x4 o;
          o[0] = (bf16_t)((float)gv[0] / (1.f + __expf(-(v4.x + bb.x))));
          o[1] = (bf16_t)((float)gv[1] / (1.f + __expf(-(v4.y + bb.y))));
          o[2] = (bf16_t)((float)gv[2] / (1.f + __expf(-(v4.z + bb.z))));
          o[3] = (bf16_t)((float)gv[3] / (1.f + __expf(-(v4.w + bb.w))));
          *(bf16x4*)((bf16_t*)Cv + goff) = o;
        } else {
          *(float4*)((float*)Cv + (long)z * sCz + goff) = v4;
        }
      }
    }
  }
}

// ---------------------------------------------------------------------------
// Flash attention, pure-causal in position space (no perm in hot loop).
// Block = 4 waves x 32 q-rows = 128 q-rows; grid (8, 256): y = zi*64 + b*16+h.
// 64-key tiles, ktiles = 2*qt+2. K from qk (pos rows), V^T from vt [d][pos].
// All LDS rows padded to 72 elems (b128 at bank floor). DPP softmax reduce.
// ---------------------------------------------------------------------------
__global__ __launch_bounds__(256, 3) void attn_k(
    const bf16_t* __restrict__ qk, long sQz,
    const bf16_t* __restrict__ vt, long sVz,
    bf16_t* __restrict__ y, long sYz, int dir0) {
  const int zi = blockIdx.y >> 6;
  const int bh = blockIdx.y & 63;
  const int dir = dir0 + zi;
  const int b = bh >> 4, h = bh & 15;
  const int qt = (int)(gridDim.x - 1 - blockIdx.x);  // heavy blocks first
  const int tid = threadIdx.x;
  const int wave = tid >> 6, lane = tid & 63;
  const int lane15 = lane & 15, quad = lane >> 4;
  const int hoff = h * 64;
  const bf16_t* base = qk + (long)zi * sQz + (long)b * 1024 * 2048;
  const bf16_t* vth = vt + (long)zi * sVz + ((long)b * 16 + h) * 64 * 1024;
  bf16_t* yd = y + (long)zi * sYz;

  __shared__ __align__(16) bf16_t sK[64 * 72];
  __shared__ __align__(16) bf16_t sVt[64 * 72];
  __shared__ __align__(16) bf16_t sP[4][32 * 72];

  // Q fragments: 2 row-groups of 16, A-layout (m=lane15, k=quad*8+j)
  bf16x8 qa[2][2];
#pragma unroll
  for (int g = 0; g < 2; g++) {
    const int row = qt * 128 + wave * 32 + g * 16 + lane15;
    qa[g][0] = *(const bf16x8*)(base + (long)row * 2048 + hoff + quad * 8);
    qa[g][1] = *(const bf16x8*)(base + (long)row * 2048 + hoff + 32 + quad * 8);
  }

  const float FNEG = -1e30f;
  float mrow[2][4], lrow[2][4];
  f32x4 o[2][4];
#pragma unroll
  for (int g = 0; g < 2; g++)
#pragma unroll
    for (int r = 0; r < 4; r++) { mrow[g][r] = FNEG; lrow[g][r] = 0.f; }
#pragma unroll
  for (int g = 0; g < 2; g++)
#pragma unroll
    for (int d4 = 0; d4 < 4; d4++) o[g][d4] = (f32x4){0.f, 0.f, 0.f, 0.f};

  const int krow = tid >> 3, kd = (tid & 7) * 8;   // K: 32 rows x 128B per pass
  const int vd = tid >> 2, pc = (tid & 3) * 8;     // V: 64 d-rows x 64B per pass
  const bf16_t* kb_g = base + 1024 + hoff;

  // preload tile 0
  bf16x8 kA = *(const bf16x8*)(kb_g + (long)krow * 2048 + kd);
  bf16x8 kB = *(const bf16x8*)(kb_g + (long)(32 + krow) * 2048 + kd);
  bf16x8 vA = *(const bf16x8*)(vth + (long)vd * 1024 + pc);
  bf16x8 vB = *(const bf16x8*)(vth + (long)vd * 1024 + 32 + pc);

  const int ktiles = 2 * qt + 2;
  for (int kt = 0; kt < ktiles; kt++) {
    __syncthreads();  // prev tile's LDS reads done
    *(bf16x8*)&sK[krow * 72 + kd] = kA;
    *(bf16x8*)&sK[(krow + 32) * 72 + kd] = kB;
    *(bf16x8*)&sVt[vd * 72 + pc] = vA;
    *(bf16x8*)&sVt[vd * 72 + 32 + pc] = vB;
    __syncthreads();  // staging visible
    if (kt + 1 < ktiles) {  // prefetch next tile into regs (overlaps compute)
      const int nb = (kt + 1) * 64;
      kA = *(const bf16x8*)(kb_g + (long)(nb + krow) * 2048 + kd);
      kB = *(const bf16x8*)(kb_g + (long)(nb + 32 + krow) * 2048 + kd);
      vA = *(const bf16x8*)(vth + (long)vd * 1024 + nb + pc);
      vB = *(const bf16x8*)(vth + (long)vd * 1024 + nb + 32 + pc);
    }
    const int kbase = kt * 64;

    // S = Q K^T: per g, 4 key-groups x 2 k-chunks
    bf16x8 kb[4][2];
#pragma unroll
    for (int ns = 0; ns < 4; ns++) {
      kb[ns][0] = *(const bf16x8*)&sK[(ns * 16 + lane15) * 72 + quad * 8];
      kb[ns][1] = *(const bf16x8*)&sK[(ns * 16 + lane15) * 72 + 32 + quad * 8];
    }
    f32x4 s[2][4];
#pragma unroll
    for (int g = 0; g < 2; g++)
#pragma unroll
      for (int ns = 0; ns < 4; ns++) {
        f32x4 t = (f32x4){0.f, 0.f, 0.f, 0.f};
        t = MFMA16(qa[g][0], kb[ns][0], t);
        t = MFMA16(qa[g][1], kb[ns][1], t);
        s[g][ns] = t;
      }
    // scale + causal mask
#pragma unroll
    for (int g = 0; g < 2; g++) {
      const int qc = qt * 128 + wave * 32 + g * 16 + quad * 4;
#pragma unroll
      for (int ns = 0; ns < 4; ns++) {
        const int kp = kbase + ns * 16 + lane15;
#pragma unroll
        for (int r = 0; r < 4; r++) {
          const float v = s[g][ns][r] * 0.125f;
          s[g][ns][r] = (kp <= qc + r) ? v : FNEG;
        }
      }
    }
    // online softmax (DPP 16-lane reductions)
#pragma unroll
    for (int g = 0; g < 2; g++) {
      float alpha[4];
#pragma unroll
      for (int r = 0; r < 4; r++) {
        float tm = fmaxf(fmaxf(s[g][0][r], s[g][1][r]),
                         fmaxf(s[g][2][r], s[g][3][r]));
        tm = dpp_max16(tm);
        const float mn = fmaxf(mrow[g][r], tm);
        alpha[r] = __expf(mrow[g][r] - mn);
        mrow[g][r] = mn;
      }
#pragma unroll
      for (int ns = 0; ns < 4; ns++)
#pragma unroll
        for (int r = 0; r < 4; r++)
          s[g][ns][r] = __expf(s[g][ns][r] - mrow[g][r]);
#pragma unroll
      for (int r = 0; r < 4; r++) {
        float ts = (s[g][0][r] + s[g][1][r]) + (s[g][2][r] + s[g][3][r]);
        ts = dpp_sum16(ts);
        lrow[g][r] = lrow[g][r] * alpha[r] + ts;
      }
#pragma unroll
      for (int d4 = 0; d4 < 4; d4++)
#pragma unroll
        for (int r = 0; r < 4; r++) o[g][d4][r] *= alpha[r];
      // P: C-layout -> bf16 A-layout via per-wave LDS scratch
#pragma unroll
      for (int ns = 0; ns < 4; ns++)
#pragma unroll
        for (int r = 0; r < 4; r++)
          sP[wave][(g * 16 + quad * 4 + r) * 72 + ns * 16 + lane15] =
              (bf16_t)s[g][ns][r];
    }
    // PV
    bf16x8 vb[4][2];
#pragma unroll
    for (int d4 = 0; d4 < 4; d4++) {
      vb[d4][0] = *(const bf16x8*)&sVt[(d4 * 16 + lane15) * 72 + quad * 8];
      vb[d4][1] = *(const bf16x8*)&sVt[(d4 * 16 + lane15) * 72 + 32 + quad * 8];
    }
#pragma unroll
    for (int g = 0; g < 2; g++) {
      const bf16x8 pa0 = *(const bf16x8*)&sP[wave][(g * 16 + lane15) * 72 + quad * 8];
      const bf16x8 pa1 = *(const bf16x8*)&sP[wave][(g * 16 + lane15) * 72 + 32 + quad * 8];
#pragma unroll
      for (int d4 = 0; d4 < 4; d4++) {
        o[g][d4] = MFMA16(pa0, vb[d4][0], o[g][d4]);
        o[g][d4] = MFMA16(pa1, vb[d4][1], o[g][d4]);
      }
    }
  }

  // epilogue: normalize, bounce through sP (per-wave), vector store, token scatter
#pragma unroll
  for (int g = 0; g < 2; g++)
#pragma unroll
    for (int r = 0; r < 4; r++) {
      const float rinv = 1.f / fmaxf(lrow[g][r], 1e-20f);
#pragma unroll
      for (int d4 = 0; d4 < 4; d4++)
        sP[wave][(g * 16 + quad * 4 + r) * 72 + d4 * 16 + lane15] =
            (bf16_t)(o[g][d4][r] * rinv);
    }
#pragma unroll
  for (int g = 0; g < 2; g++) {
    const bf16x8 o0 = *(const bf16x8*)&sP[wave][(g * 16 + lane15) * 72 + quad * 16];
    const bf16x8 o1 = *(const bf16x8*)&sP[wave][(g * 16 + lane15) * 72 + quad * 16 + 8];
    const int tok = perm_t(qt * 128 + wave * 32 + g * 16 + lane15, dir);
    bf16_t* yr = yd + ((long)b * 1024 + tok) * 1024 + hoff + quad * 16;
    *(bf16x8*)yr = o0;
    *(bf16x8*)(yr + 8) = o1;
  }
}

// ---------------------------------------------------------------------------
// RMSNorm over rows of 1024: v = P0 + P1 + x (split-K reduce + residual).
// ---------------------------------------------------------------------------
__global__ __launch_bounds__(256) void rmsnorm_k(const float* __restrict__ p0,
                                                 const float* __restrict__ p1,
                                                 const float* __restrict__ x,
                                                 const float* __restrict__ w,
                                                 float* __restrict__ out) {
  const int row = blockIdx.x, tid = threadIdx.x;
  const long off = (long)row * 1024;
  const float4 a = ((const float4*)(p0 + off))[tid];
  const float4 bq = ((const float4*)(p1 + off))[tid];
  const float4 c = ((const float4*)(x + off))[tid];
  float4 v;
  v.x = a.x + bq.x + c.x;
  v.y = a.y + bq.y + c.y;
  v.z = a.z + bq.z + c.z;
  v.w = a.w + bq.w + c.w;
  float ss = v.x * v.x + v.y * v.y + v.z * v.z + v.w * v.w;
#pragma unroll
  for (int o2 = 32; o2 >= 1; o2 >>= 1) ss += __shfl_xor(ss, o2);
  __shared__ float wsum[4];
  if ((tid & 63) == 0) wsum[tid >> 6] = ss;
  __syncthreads();
  const float tot = wsum[0] + wsum[1] + wsum[2] + wsum[3];
  const float norm = rsqrtf(tot * (1.f / 1024.f) + 1e-6f);
  const float4 wv = ((const float4*)w)[tid];
  v.x = v.x * norm * wv.x;
  v.y = v.y * norm * wv.y;
  v.z = v.z * norm * wv.z;
  v.w = v.w * norm * wv.w;
  ((float4*)(out + off))[tid] = v;
}

// ---------------------------------------------------------------------------
extern "C" void kernel_launch(void* const* d_in, const int* in_sizes, int n_in,
                              void* d_out, int out_size, void* d_ws, size_t ws_size,
                              hipStream_t stream) {
  (void)in_sizes; (void)n_in; (void)out_size;
  const float* xf = (const float*)d_in[0];
  const float* wqkv_f[4] = {(const float*)d_in[1], (const float*)d_in[3],
                            (const float*)d_in[5], (const float*)d_in[7]};
  const float* wo_f[4] = {(const float*)d_in[2], (const float*)d_in[4],
                          (const float*)d_in[6], (const float*)d_in[8]};
  const float* wgate_f = (const float*)d_in[9];
  const float* bgate_f = (const float*)d_in[10];
  const float* wout_f = (const float*)d_in[11];
  const float* normw_f = (const float*)d_in[12];

  const long MB = 1l << 20;
  char* ws = (char*)d_ws;
  const dim3 blk(256);
  const bool batched = ws_size >= (size_t)(168 * MB);
  const long sQK = 4096l * 2048;   // qk per-dir elems (16 MB)
  const long sVT = 4096l * 1024;   // vt per-dir elems (8 MB)
  const long sY  = 4096l * 1024;   // y per-dir elems (8 MB)

  if (batched) {
    bf16_t* x_c    = (bf16_t*)(ws);              // 8 MB   -> wout_c later
    bf16_t* wq_c   = (bf16_t*)(ws + 8 * MB);     // 24 MB
    bf16_t* wo_c   = (bf16_t*)(ws + 32 * MB);    // 8 MB
    bf16_t* qk     = (bf16_t*)(ws + 40 * MB);    // 64 MB (4 dirs, pos order)
    bf16_t* vt     = (bf16_t*)(ws + 104 * MB);   // 32 MB (4 dirs, [b][h][d][p])
    bf16_t* y      = (bf16_t*)(ws + 136 * MB);   // 32 MB -> gated
    bf16_t* concat = (bf16_t*)(ws + 40 * MB);    // 32 MB (phase 2, qk dirs 0-1 dead)
    bf16_t* wg_c   = (bf16_t*)(ws + 72 * MB);    // 32 MB (qk dirs 2-3 dead)
    bf16_t* wout_c = (bf16_t*)(ws);              // 8 MB (x dead)
    float*  part   = (float*)(ws + 104 * MB);    // 32 MB (vt dead)
    bf16_t* gated  = y;

    {  // convert x, wqkv x4, wo x4
      CvtDesc cd;
      cd.src[0] = xf; cd.dst[0] = x_c; cd.n8[0] = 4194304 / 8;
      for (int d = 0; d < 4; d++) {
        cd.src[1 + d] = wqkv_f[d];
        cd.dst[1 + d] = wq_c + (long)d * 3145728;
        cd.n8[1 + d] = 3145728 / 8;
        cd.src[5 + d] = wo_f[d];
        cd.dst[5 + d] = wo_c + (long)d * 1048576;
        cd.n8[5 + d] = 1048576 / 8;
      }
      cvt9_k<<<dim3(2048, 9), blk, 0, stream>>>(cd);
    }
    {  // qkv GEMM, 4 dirs: Q,K -> pos order; V -> vt transposed
      Ptr4 bq{{wq_c, wq_c + 3145728, wq_c + 2l * 3145728, wq_c + 3l * 3145728}};
      gemm_bt<4><<<dim3(24, 32, 4), blk, 0, stream>>>(
          x_c, 0, 1024, bq, 1024, qk, sQK, 2048, 1024, 0, nullptr, nullptr,
          vt, sVT, 0);
    }
    attn_k<<<dim3(8, 256), blk, 0, stream>>>(qk, sQK, vt, sVT, y, sY, 0);
    {  // convert wgate + wout (after attn: overlays qk/x space)
      CvtDesc cd;
      for (int s = 0; s < 9; s++) cd.n8[s] = 0;
      cd.src[0] = wgate_f; cd.dst[0] = wg_c; cd.n8[0] = 16777216 / 8;
      cd.src[1] = wout_f; cd.dst[1] = wout_c; cd.n8[1] = 4194304 / 8;
      cvt9_k<<<dim3(8192, 2), blk, 0, stream>>>(cd);
    }
    {  // out-proj, z-batched -> concat[:, z*1024:(z+1)*1024]
      Ptr4 b4{{wo_c, wo_c + 1048576, wo_c + 2097152, wo_c + 3145728}};
      gemm_bt<0><<<dim3(8, 32, 4), blk, 0, stream>>>(
          y, sY, 1024, b4, 1024, concat, 1024, 4096, 1024, 0, nullptr, nullptr,
          nullptr, 0, 0);
    }
    {  // gated = sigmoid(concat@wg^T + b) * concat
      Ptr4 b4{{wg_c, wg_c, wg_c, wg_c}};
      gemm_bt<1><<<dim3(32, 32, 1), blk, 0, stream>>>(
          concat, 0, 4096, b4, 4096, gated, 0, 4096, 4096, 0, bgate_f, concat,
          nullptr, 0, 0);
    }
    {  // split-K=2 w_out partials
      Ptr4 b4{{wout_c, wout_c, wout_c, wout_c}};
      gemm_bt<3><<<dim3(8, 32, 2), blk, 0, stream>>>(
          gated, 0, 4096, b4, 4096, part, (long)4096 * 1024, 1024, 2048, 2048,
          nullptr, nullptr, nullptr, 0, 0);
    }
    rmsnorm_k<<<dim3(4096), blk, 0, stream>>>(part, part + (long)4096 * 1024,
                                              xf, normw_f, (float*)d_out);
  } else {
    // fallback (96 MB): per-dir qkv+attn
    bf16_t* x_c    = (bf16_t*)(ws);              // 8 MB
    bf16_t* wq_c   = (bf16_t*)(ws + 8 * MB);     // 24 MB
    bf16_t* qk_d   = (bf16_t*)(ws + 32 * MB);    // 16 MB (per-dir)
    bf16_t* vt_d   = (bf16_t*)(ws + 48 * MB);    // 8 MB (per-dir)
    bf16_t* wo_c   = (bf16_t*)(ws + 56 * MB);    // 8 MB
    bf16_t* y      = (bf16_t*)(ws + 64 * MB);    // 32 MB -> gated
    bf16_t* concat = (bf16_t*)(ws);              // 32 MB (phase 2)
    bf16_t* wg_c   = (bf16_t*)(ws + 32 * MB);    // 32 MB (after out-proj)
    bf16_t* wout_c = (bf16_t*)(ws);              // 8 MB (after gate)
    float*  part   = (float*)(ws + 8 * MB);      // 32 MB
    bf16_t* gated  = y;

    {
      CvtDesc cd;
      cd.src[0] = xf; cd.dst[0] = x_c; cd.n8[0] = 4194304 / 8;
      for (int d = 0; d < 4; d++) {
        cd.src[1 + d] = wqkv_f[d];
        cd.dst[1 + d] = wq_c + (long)d * 3145728;
        cd.n8[1 + d] = 3145728 / 8;
        cd.src[5 + d] = wo_f[d];
        cd.dst[5 + d] = wo_c + (long)d * 1048576;
        cd.n8[5 + d] = 1048576 / 8;
      }
      cvt9_k<<<dim3(2048, 9), blk, 0, stream>>>(cd);
    }
    for (int d = 0; d < 4; d++) {
      const bf16_t* wq_d = wq_c + (long)d * 3145728;
      Ptr4 bq{{wq_d, wq_d, wq_d, wq_d}};
      gemm_bt<4><<<dim3(24, 32, 1), blk, 0, stream>>>(
          x_c, 0, 1024, bq, 1024, qk_d, 0, 2048, 1024, 0, nullptr, nullptr,
          vt_d, 0, d);
      attn_k<<<dim3(8, 64), blk, 0, stream>>>(qk_d, 0, vt_d, 0,
                                              y + (long)d * sY, 0, d);
    }
    {
      Ptr4 b4{{wo_c, wo_c + 1048576, wo_c + 2097152, wo_c + 3145728}};
      gemm_bt<0><<<dim3(8, 32, 4), blk, 0, stream>>>(
          y, sY, 1024, b4, 1024, concat, 1024, 4096, 1024, 0, nullptr, nullptr,
          nullptr, 0, 0);
    }
    {
      CvtDesc cd;
      for (int s = 0; s < 9; s++) cd.n8[s] = 0;
      cd.src[0] = wgate_f; cd.dst[0] = wg_c; cd.n8[0] = 16777216 / 8;
      cvt9_k<<<dim3(8192, 1), blk, 0, stream>>>(cd);
    }
    {
      Ptr4 b4{{wg_c, wg_c, wg_c, wg_c}};
      gemm_bt<1><<<dim3(32, 32, 1), blk, 0, stream>>>(
          concat, 0, 4096, b4, 4096, gated, 0, 4096, 4096, 0, bgate_f, concat,
          nullptr, 0, 0);
    }
    {
      CvtDesc cd;
      for (int s = 0; s < 9; s++) cd.n8[s] = 0;
      cd.src[0] = wout_f; cd.dst[0] = wout_c; cd.n8[0] = 4194304 / 8;
      cvt9_k<<<dim3(2048, 1), blk, 0, stream>>>(cd);
    }
    {
      Ptr4 b4{{wout_c, wout_c, wout_c, wout_c}};
      gemm_bt<3><<<dim3(8, 32, 2), blk, 0, stream>>>(
          gated, 0, 4096, b4, 4096, part, (long)4096 * 1024, 1024, 2048, 2048,
          nullptr, nullptr, nullptr, 0, 0);
    }
    rmsnorm_k<<<dim3(4096), blk, 0, stream>>>(part, part + (long)4096 * 1024,
                                              xf, normw_f, (float*)d_out);
  }
}